// Round 2
// baseline (1777.048 us; speedup 1.0000x reference)
//
#include <hip/hip_runtime.h>
#include <hip/hip_bf16.h>

#define HD 2048
#define SEQ 1024
#define NHEAD 32
#define NKVH 8
#define DHEAD 64
#define NEXP 8
#define INTER 2048
#define SCALE 0.125f
#define ALPHA 1.702f
#define LIMIT 7.0f

typedef __attribute__((ext_vector_type(8))) short short8;
typedef __attribute__((ext_vector_type(4))) short short4v;
typedef __attribute__((ext_vector_type(4))) float f32x4;

__device__ __forceinline__ unsigned short f2bf(float f) {
  union { float f; unsigned u; } v; v.f = f;
  unsigned r = v.u + 0x7fffu + ((v.u >> 16) & 1u);
  return (unsigned short)(r >> 16);
}
__device__ __forceinline__ float bf2f(unsigned short h) {
  union { unsigned u; float f; } v; v.u = ((unsigned)h) << 16; return v.f;
}
__device__ __forceinline__ void split2(float f, unsigned short& hi, unsigned short& lo) {
  hi = f2bf(f);
  lo = f2bf(f - bf2f(hi));
}

__device__ __forceinline__ f32x4 mfma32(short8 a, short8 b, f32x4 c) {
  return __builtin_amdgcn_mfma_f32_16x16x32_bf16(a, b, c, 0, 0, 0);
}

// ---------------- RMSNorm fp32 -> split bf16 (hi/lo) ----------------
__global__ __launch_bounds__(256) void rmsnorm_split_kernel(
    const float* __restrict__ x, const float* __restrict__ gamma,
    unsigned short* __restrict__ oh, unsigned short* __restrict__ ol) {
  int row = blockIdx.x, tid = threadIdx.x;
  const float* xr = x + (size_t)row * HD;
  float v[8];
#pragma unroll
  for (int i = 0; i < 8; ++i) v[i] = xr[tid * 8 + i];
  float ss = 0.f;
#pragma unroll
  for (int i = 0; i < 8; ++i) ss += v[i] * v[i];
#pragma unroll
  for (int off = 32; off; off >>= 1) ss += __shfl_xor(ss, off, 64);
  __shared__ float wss[4];
  if ((tid & 63) == 0) wss[tid >> 6] = ss;
  __syncthreads();
  float rs = rsqrtf((wss[0] + wss[1] + wss[2] + wss[3]) * (1.0f / HD) + 1e-5f);
  short8 vh, vl;
#pragma unroll
  for (int i = 0; i < 8; ++i) {
    float val = v[i] * rs * gamma[tid * 8 + i];
    unsigned short h, lo;
    split2(val, h, lo);
    vh[i] = (short)h;
    vl[i] = (short)lo;
  }
  *(short8*)(oh + (size_t)row * HD + tid * 8) = vh;
  *(short8*)(ol + (size_t)row * HD + tid * 8) = vl;
}

// ---------------- RMSNorm fp32 -> single bf16 (MoE input) ----------------
__global__ __launch_bounds__(256) void rmsnorm_plain_kernel(
    const float* __restrict__ x, const float* __restrict__ gamma,
    unsigned short* __restrict__ out) {
  int row = blockIdx.x, tid = threadIdx.x;
  const float* xr = x + (size_t)row * HD;
  float v[8];
#pragma unroll
  for (int i = 0; i < 8; ++i) v[i] = xr[tid * 8 + i];
  float ss = 0.f;
#pragma unroll
  for (int i = 0; i < 8; ++i) ss += v[i] * v[i];
#pragma unroll
  for (int off = 32; off; off >>= 1) ss += __shfl_xor(ss, off, 64);
  __shared__ float wss[4];
  if ((tid & 63) == 0) wss[tid >> 6] = ss;
  __syncthreads();
  float rs = rsqrtf((wss[0] + wss[1] + wss[2] + wss[3]) * (1.0f / HD) + 1e-5f);
  short8 o;
#pragma unroll
  for (int i = 0; i < 8; ++i) o[i] = (short)f2bf(v[i] * rs * gamma[tid * 8 + i]);
  *(short8*)(out + (size_t)row * HD + tid * 8) = o;
}

// ---------------- Split-precision GEMM: out[m,n] = A[m,:]·W[n,:] + b[n] ------
// acc = Ah*Wh + Ah*Wl + Al*Wh  (double-bf16, ~2^-17.5 relative)
// MODE 0: split bf16 out [M,N]; MODE 1: split bf16 out transposed [N,M];
// MODE 2: fp32 out = val + resid -> outf and outf2.
template <int MODE>
__global__ __launch_bounds__(256) void gemm_split(
    const unsigned short* __restrict__ Ah, const unsigned short* __restrict__ Al,
    const float* __restrict__ W, const float* __restrict__ bias,
    const float* __restrict__ resid, unsigned short* __restrict__ outh,
    unsigned short* __restrict__ outl, float* __restrict__ outf,
    float* __restrict__ outf2, int M, int N, int Kd) {
  int l = threadIdx.x & 63, w = threadIdx.x >> 6;
  int g = l >> 4, q = l & 15;
  int n0 = blockIdx.x * 16;
  int m0 = blockIdx.y * 64 + w * 16;
  const unsigned short* aph = Ah + (size_t)(m0 + q) * Kd + 8 * g;
  const unsigned short* apl = Al + (size_t)(m0 + q) * Kd + 8 * g;
  const float* wp = W + (size_t)(n0 + q) * Kd + 8 * g;
  f32x4 acc = {0.f, 0.f, 0.f, 0.f};
#pragma unroll 2
  for (int k = 0; k < Kd; k += 32) {
    short8 ah = *(const short8*)(aph + k);
    short8 al = *(const short8*)(apl + k);
    const float* wk = wp + k;
    short8 wh, wl;
#pragma unroll
    for (int j = 0; j < 8; ++j) {
      unsigned short h, lo;
      split2(wk[j], h, lo);
      wh[j] = (short)h;
      wl[j] = (short)lo;
    }
    acc = mfma32(ah, wh, acc);
    acc = mfma32(ah, wl, acc);
    acc = mfma32(al, wh, acc);
  }
  int n = n0 + q;
  float bs = bias[n];
#pragma unroll
  for (int r = 0; r < 4; ++r) {
    int mr = m0 + 4 * g + r;
    float val = acc[r] + bs;
    if (MODE == 0) {
      unsigned short h, lo;
      split2(val, h, lo);
      outh[(size_t)mr * N + n] = h;
      outl[(size_t)mr * N + n] = lo;
    } else if (MODE == 1) {
      unsigned short h, lo;
      split2(val, h, lo);
      outh[(size_t)n * M + mr] = h;
      outl[(size_t)n * M + mr] = lo;
    } else {
      float vv = val + resid[(size_t)mr * N + n];
      outf[(size_t)mr * N + n] = vv;
      outf2[(size_t)mr * N + n] = vv;
    }
  }
}

// ---------------- Flash attention with sink, split precision ----------------
__global__ __launch_bounds__(256) void attn_kernel(
    const unsigned short* __restrict__ Qh, const unsigned short* __restrict__ Ql,
    const unsigned short* __restrict__ Kh, const unsigned short* __restrict__ Kl,
    const unsigned short* __restrict__ Vh, const unsigned short* __restrict__ Vl,
    const float* __restrict__ sinks, unsigned short* __restrict__ outh,
    unsigned short* __restrict__ outl) {
  // P staged through LDS row-major [q][32 keys] so both PV operands use the
  // standard contiguous-8 load pattern (fragment k-mapping cancels).
  __shared__ __align__(16) unsigned short pbuf[4][2][16][40];
  int l = threadIdx.x & 63, widx = threadIdx.x >> 6;
  int wid = blockIdx.x * 4 + widx;
  int head = wid >> 6, qt = wid & 63;
  int q0 = qt * 16;
  int g = l >> 4, q = l & 15;
  int kvh = head >> 2;
  size_t qoff = (size_t)(q0 + q) * (NHEAD * DHEAD) + head * DHEAD + 8 * g;
  short8 qh0 = *(const short8*)(Qh + qoff);
  short8 qh1 = *(const short8*)(Qh + qoff + 32);
  short8 ql0 = *(const short8*)(Ql + qoff);
  short8 ql1 = *(const short8*)(Ql + qoff + 32);
  float m = sinks[head];  // online softmax init: sink contributes exp(0)=1
  float lsum = 1.0f;
  f32x4 o[4] = {{0, 0, 0, 0}, {0, 0, 0, 0}, {0, 0, 0, 0}, {0, 0, 0, 0}};
  int qglob = q0 + q;
  for (int kt = 0; kt <= qt; kt += 2) {
    bool hasB = (kt + 1) <= qt;
    size_t koff = (size_t)(kt * 16 + q) * (NKVH * DHEAD) + kvh * DHEAD + 8 * g;
    f32x4 stA = {0, 0, 0, 0};
    {
      short8 kh0 = *(const short8*)(Kh + koff);
      short8 kh1 = *(const short8*)(Kh + koff + 32);
      short8 kl0 = *(const short8*)(Kl + koff);
      short8 kl1 = *(const short8*)(Kl + koff + 32);
      stA = mfma32(kh0, qh0, stA);
      stA = mfma32(kh0, ql0, stA);
      stA = mfma32(kl0, qh0, stA);
      stA = mfma32(kh1, qh1, stA);
      stA = mfma32(kh1, ql1, stA);
      stA = mfma32(kl1, qh1, stA);
    }
    f32x4 stB = {0, 0, 0, 0};
    if (hasB) {
      size_t koff2 = koff + (size_t)16 * (NKVH * DHEAD);
      short8 kh0 = *(const short8*)(Kh + koff2);
      short8 kh1 = *(const short8*)(Kh + koff2 + 32);
      short8 kl0 = *(const short8*)(Kl + koff2);
      short8 kl1 = *(const short8*)(Kl + koff2 + 32);
      stB = mfma32(kh0, qh0, stB);
      stB = mfma32(kh0, ql0, stB);
      stB = mfma32(kl0, qh0, stB);
      stB = mfma32(kh1, qh1, stB);
      stB = mfma32(kh1, ql1, stB);
      stB = mfma32(kl1, qh1, stB);
    }
    float sA[4], sB[4];
#pragma unroll
    for (int r = 0; r < 4; ++r) {
      int keyA = kt * 16 + 4 * g + r;
      sA[r] = (keyA <= qglob) ? stA[r] * SCALE : -1e30f;
      sB[r] = (hasB && keyA + 16 <= qglob) ? stB[r] * SCALE : -1e30f;
    }
    float mt = fmaxf(fmaxf(fmaxf(sA[0], sA[1]), fmaxf(sA[2], sA[3])),
                     fmaxf(fmaxf(sB[0], sB[1]), fmaxf(sB[2], sB[3])));
    mt = fmaxf(mt, __shfl_xor(mt, 16, 64));
    mt = fmaxf(mt, __shfl_xor(mt, 32, 64));
    float mnew = fmaxf(m, mt);
    float corr = __expf(m - mnew);
    float pA[4], pB[4];
    float rsum = 0.f;
#pragma unroll
    for (int r = 0; r < 4; ++r) {
      pA[r] = __expf(sA[r] - mnew);
      pB[r] = __expf(sB[r] - mnew);
      rsum += pA[r] + pB[r];
    }
    rsum += __shfl_xor(rsum, 16, 64);
    rsum += __shfl_xor(rsum, 32, 64);
    lsum = lsum * corr + rsum;
    m = mnew;
#pragma unroll
    for (int dt = 0; dt < 4; ++dt)
#pragma unroll
      for (int r = 0; r < 4; ++r) o[dt][r] *= corr;
    // split P and stage via LDS: row q, cols = key offsets in [0,32)
    unsigned short ph[8], pl[8];
#pragma unroll
    for (int r = 0; r < 4; ++r) {
      split2(pA[r], ph[r], pl[r]);
      split2(pB[r], ph[4 + r], pl[4 + r]);
    }
    short4v wAh = {(short)ph[0], (short)ph[1], (short)ph[2], (short)ph[3]};
    short4v wBh = {(short)ph[4], (short)ph[5], (short)ph[6], (short)ph[7]};
    short4v wAl = {(short)pl[0], (short)pl[1], (short)pl[2], (short)pl[3]};
    short4v wBl = {(short)pl[4], (short)pl[5], (short)pl[6], (short)pl[7]};
    *(short4v*)&pbuf[widx][0][q][4 * g] = wAh;       // tile-A keys 4g..4g+3
    *(short4v*)&pbuf[widx][0][q][16 + 4 * g] = wBh;  // tile-B keys
    *(short4v*)&pbuf[widx][1][q][4 * g] = wAl;
    *(short4v*)&pbuf[widx][1][q][16 + 4 * g] = wBl;
    asm volatile("s_waitcnt lgkmcnt(0)" ::: "memory");
    short8 pbh = *(const short8*)&pbuf[widx][0][q][8 * g];
    short8 pbl = *(const short8*)&pbuf[widx][1][q][8 * g];
    size_t vbase = (size_t)(kvh * DHEAD) * SEQ + kt * 16 + 8 * g;
#pragma unroll
    for (int dt = 0; dt < 4; ++dt) {
      size_t voff = vbase + (size_t)(dt * 16 + q) * SEQ;
      short8 vh8 = *(const short8*)(Vh + voff);
      short8 vl8 = *(const short8*)(Vl + voff);
      o[dt] = mfma32(vh8, pbh, o[dt]);
      o[dt] = mfma32(vh8, pbl, o[dt]);
      o[dt] = mfma32(vl8, pbh, o[dt]);
    }
  }
  float inv = 1.0f / lsum;
#pragma unroll
  for (int dt = 0; dt < 4; ++dt)
#pragma unroll
    for (int r = 0; r < 4; ++r) {
      float val = o[dt][r] * inv;
      unsigned short h, lo;
      split2(val, h, lo);
      size_t idx = (size_t)qglob * (NHEAD * DHEAD) + head * DHEAD + dt * 16 + 4 * g + r;
      outh[idx] = h;
      outl[idx] = lo;
    }
}

// ---------------- Router: fp64 norm + logits, top-2, build expert lists ------
__global__ __launch_bounds__(64) void router_kernel(
    const float* __restrict__ h, const float* __restrict__ gamma,
    const float* __restrict__ rw, const float* __restrict__ rb,
    float* __restrict__ wts, int* __restrict__ counts, int* __restrict__ lists) {
  int t = blockIdx.x;
  int l = threadIdx.x;
  const float* hr = h + (size_t)t * HD;
  double ss = 0.0;
  for (int i = l; i < HD; i += 64) {
    double x = (double)hr[i];
    ss += x * x;
  }
#pragma unroll
  for (int off = 32; off; off >>= 1) ss += __shfl_xor(ss, off, 64);
  double rs = rsqrt(ss * (1.0 / HD) + 1e-5);
  double acc[NEXP];
#pragma unroll
  for (int e = 0; e < NEXP; ++e) acc[e] = 0.0;
  for (int i = l; i < HD; i += 64) {
    double xh = (double)hr[i] * rs * (double)gamma[i];
#pragma unroll
    for (int e = 0; e < NEXP; ++e) acc[e] += xh * (double)rw[e * HD + i];
  }
#pragma unroll
  for (int e = 0; e < NEXP; ++e)
#pragma unroll
    for (int off = 32; off; off >>= 1) acc[e] += __shfl_xor(acc[e], off, 64);
  if (l == 0) {
    double lg[NEXP];
#pragma unroll
    for (int e = 0; e < NEXP; ++e) lg[e] = acc[e] + (double)rb[e];
    int e0 = 0;
#pragma unroll
    for (int e = 1; e < NEXP; ++e)
      if (lg[e] > lg[e0]) e0 = e;
    int e1 = -1;
#pragma unroll
    for (int e = 0; e < NEXP; ++e)
      if (e != e0 && (e1 < 0 || lg[e] > lg[e1])) e1 = e;
    double d = exp(lg[e1] - lg[e0]);
    float p0 = (float)(1.0 / (1.0 + d)), p1 = (float)(d / (1.0 + d));
#pragma unroll
    for (int e = 0; e < NEXP; ++e)
      wts[t * NEXP + e] = (e == e0) ? p0 : (e == e1) ? p1 : 0.f;
    int s0 = atomicAdd(&counts[e0], 1);
    lists[e0 * SEQ + s0] = t;
    int s1 = atomicAdd(&counts[e1], 1);
    lists[e1 * SEQ + s1] = t;
  }
}

// ---------------- MoE gate/up grouped GEMM + activation (m-loop inside) ------
__global__ __launch_bounds__(256) void gemm_gateup(
    const unsigned short* __restrict__ hn, const float* __restrict__ Wg,
    const float* __restrict__ bg, const float* __restrict__ Wu,
    const float* __restrict__ bu, const int* __restrict__ counts,
    const int* __restrict__ lists, unsigned short* __restrict__ gated) {
  int e = blockIdx.z;
  int count = counts[e];
  int l = threadIdx.x & 63, w = threadIdx.x >> 6;
  int g = l >> 4, q = l & 15;
  int n0 = blockIdx.x * 16;
  int n = n0 + q;
  const float* wgp = Wg + ((size_t)e * INTER + n0 + q) * HD + 8 * g;
  const float* wup = Wu + ((size_t)e * INTER + n0 + q) * HD + 8 * g;
  float bgs = bg[e * INTER + n], bus = bu[e * INTER + n];
  for (int mt = 0; mt * 64 < count; ++mt) {
    int m0 = mt * 64 + w * 16;
    int tok = lists[e * SEQ + min(m0 + q, count - 1)];
    const unsigned short* ap = hn + (size_t)tok * HD + 8 * g;
    f32x4 ag = {0, 0, 0, 0}, au = {0, 0, 0, 0};
#pragma unroll 2
    for (int k = 0; k < HD; k += 32) {
      short8 a = *(const short8*)(ap + k);
      const float* wg = wgp + k;
      const float* wu = wup + k;
      short8 bgf, buf;
#pragma unroll
      for (int j = 0; j < 8; ++j) {
        bgf[j] = (short)f2bf(wg[j]);
        buf[j] = (short)f2bf(wu[j]);
      }
      ag = mfma32(a, bgf, ag);
      au = mfma32(a, buf, au);
    }
#pragma unroll
    for (int r = 0; r < 4; ++r) {
      int mm = m0 + 4 * g + r;
      if (mm < count) {
        float gate = ag[r] + bgs, up = au[r] + bus;
        float gc = fminf(gate, LIMIT);
        float uc = fminf(fmaxf(up, -LIMIT), LIMIT);
        float glu = gc / (1.f + __expf(-ALPHA * gc));
        gated[((size_t)e * SEQ + mm) * INTER + n] = f2bf((uc + 1.f) * glu);
      }
    }
  }
}

// ---------------- MoE down grouped GEMM (m-loop inside), weighted atomics ----
__global__ __launch_bounds__(256) void gemm_down(
    const unsigned short* __restrict__ gated, const float* __restrict__ Wd,
    const float* __restrict__ bd, const int* __restrict__ counts,
    const int* __restrict__ lists, const float* __restrict__ wts,
    float* __restrict__ out) {
  int e = blockIdx.z;
  int count = counts[e];
  int l = threadIdx.x & 63, w = threadIdx.x >> 6;
  int g = l >> 4, q = l & 15;
  int n0 = blockIdx.x * 16;
  int n = n0 + q;
  const float* wp = Wd + ((size_t)e * HD + n0 + q) * INTER + 8 * g;
  float bds = bd[e * HD + n];
  for (int mt = 0; mt * 64 < count; ++mt) {
    int m0 = mt * 64 + w * 16;
    const unsigned short* ap =
        gated + ((size_t)e * SEQ + min(m0 + q, count - 1)) * INTER + 8 * g;
    f32x4 acc = {0, 0, 0, 0};
#pragma unroll 2
    for (int k = 0; k < INTER; k += 32) {
      short8 a = *(const short8*)(ap + k);
      const float* wk = wp + k;
      short8 b;
#pragma unroll
      for (int j = 0; j < 8; ++j) b[j] = (short)f2bf(wk[j]);
      acc = mfma32(a, b, acc);
    }
#pragma unroll
    for (int r = 0; r < 4; ++r) {
      int mm = m0 + 4 * g + r;
      if (mm < count) {
        int t = lists[e * SEQ + mm];
        float wt = wts[t * NEXP + e];
        atomicAdd(&out[(size_t)t * HD + n], (acc[r] + bds) * wt);
      }
    }
  }
}

extern "C" void kernel_launch(void* const* d_in, const int* in_sizes, int n_in,
                              void* d_out, int out_size, void* d_ws,
                              size_t ws_size, hipStream_t stream) {
  const float* x = (const float*)d_in[0];
  const float* ln1 = (const float*)d_in[2];
  const float* ln2 = (const float*)d_in[3];
  const float* Wq = (const float*)d_in[4];
  const float* bq = (const float*)d_in[5];
  const float* Wk = (const float*)d_in[6];
  const float* bk = (const float*)d_in[7];
  const float* Wv = (const float*)d_in[8];
  const float* bv = (const float*)d_in[9];
  const float* Wo = (const float*)d_in[10];
  const float* bo = (const float*)d_in[11];
  const float* sinks = (const float*)d_in[12];
  const float* rw = (const float*)d_in[13];
  const float* rb = (const float*)d_in[14];
  const float* Wg = (const float*)d_in[15];
  const float* bg = (const float*)d_in[16];
  const float* Wu = (const float*)d_in[17];
  const float* bu = (const float*)d_in[18];
  const float* Wd = (const float*)d_in[19];
  const float* bd = (const float*)d_in[20];
  float* out = (float*)d_out;

  char* ws = (char*)d_ws;
  size_t off = 0;
  auto alloc = [&](size_t bytes) {
    void* p = ws + off;
    off += (bytes + 255) & ~(size_t)255;
    return p;
  };
  unsigned short* xnh = (unsigned short*)alloc((size_t)SEQ * HD * 2);
  unsigned short* xnl = (unsigned short*)alloc((size_t)SEQ * HD * 2);
  unsigned short* qbh = (unsigned short*)alloc((size_t)SEQ * NHEAD * DHEAD * 2);
  unsigned short* qbl = (unsigned short*)alloc((size_t)SEQ * NHEAD * DHEAD * 2);
  unsigned short* kbh = (unsigned short*)alloc((size_t)SEQ * NKVH * DHEAD * 2);
  unsigned short* kbl = (unsigned short*)alloc((size_t)SEQ * NKVH * DHEAD * 2);
  unsigned short* vth = (unsigned short*)alloc((size_t)NKVH * DHEAD * SEQ * 2);
  unsigned short* vtl = (unsigned short*)alloc((size_t)NKVH * DHEAD * SEQ * 2);
  unsigned short* ath = (unsigned short*)alloc((size_t)SEQ * NHEAD * DHEAD * 2);
  unsigned short* atl = (unsigned short*)alloc((size_t)SEQ * NHEAD * DHEAD * 2);
  float* hbuf = (float*)alloc((size_t)SEQ * HD * 4);
  unsigned short* hn = (unsigned short*)alloc((size_t)SEQ * HD * 2);
  float* wts = (float*)alloc((size_t)SEQ * NEXP * 4);
  int* counts = (int*)alloc(NEXP * 4);
  int* lists = (int*)alloc((size_t)NEXP * SEQ * 4);
  unsigned short* gated = (unsigned short*)alloc((size_t)NEXP * SEQ * INTER * 2);
  (void)ws_size;
  (void)off;

  rmsnorm_split_kernel<<<SEQ, 256, 0, stream>>>(x, ln1, xnh, xnl);
  gemm_split<0><<<dim3(NHEAD * DHEAD / 16, SEQ / 64), 256, 0, stream>>>(
      xnh, xnl, Wq, bq, nullptr, qbh, qbl, nullptr, nullptr, SEQ, NHEAD * DHEAD, HD);
  gemm_split<0><<<dim3(NKVH * DHEAD / 16, SEQ / 64), 256, 0, stream>>>(
      xnh, xnl, Wk, bk, nullptr, kbh, kbl, nullptr, nullptr, SEQ, NKVH * DHEAD, HD);
  gemm_split<1><<<dim3(NKVH * DHEAD / 16, SEQ / 64), 256, 0, stream>>>(
      xnh, xnl, Wv, bv, nullptr, vth, vtl, nullptr, nullptr, SEQ, NKVH * DHEAD, HD);
  attn_kernel<<<NHEAD * 64 / 4, 256, 0, stream>>>(qbh, qbl, kbh, kbl, vth, vtl,
                                                  sinks, ath, atl);
  gemm_split<2><<<dim3(HD / 16, SEQ / 64), 256, 0, stream>>>(
      ath, atl, Wo, bo, x, nullptr, nullptr, hbuf, out, SEQ, HD, NHEAD * DHEAD);
  rmsnorm_plain_kernel<<<SEQ, 256, 0, stream>>>(hbuf, ln2, hn);
  hipMemsetAsync(counts, 0, NEXP * sizeof(int), stream);
  router_kernel<<<SEQ, 64, 0, stream>>>(hbuf, ln2, rw, rb, wts, counts, lists);
  gemm_gateup<<<dim3(INTER / 16, 1, NEXP), 256, 0, stream>>>(
      hn, Wg, bg, Wu, bu, counts, lists, gated);
  gemm_down<<<dim3(HD / 16, 1, NEXP), 256, 0, stream>>>(
      gated, Wd, bd, counts, lists, wts, out);
}

// Round 3
// 1279.365 us; speedup vs baseline: 1.3890x; 1.3890x over previous
//
#include <hip/hip_runtime.h>
#include <hip/hip_bf16.h>

#define HD 2048
#define SEQ 1024
#define NHEAD 32
#define NKVH 8
#define DHEAD 64
#define NEXP 8
#define INTER 2048
#define SCALE 0.125f
#define ALPHA 1.702f
#define LIMIT 7.0f

typedef __attribute__((ext_vector_type(8))) short short8;
typedef __attribute__((ext_vector_type(4))) short short4v;
typedef __attribute__((ext_vector_type(4))) float f32x4;

__device__ __forceinline__ unsigned short f2bf(float f) {
  union { float f; unsigned u; } v; v.f = f;
  unsigned r = v.u + 0x7fffu + ((v.u >> 16) & 1u);
  return (unsigned short)(r >> 16);
}
__device__ __forceinline__ float bf2f(unsigned short h) {
  union { unsigned u; float f; } v; v.u = ((unsigned)h) << 16; return v.f;
}
__device__ __forceinline__ void split2(float f, unsigned short& hi, unsigned short& lo) {
  hi = f2bf(f);
  lo = f2bf(f - bf2f(hi));
}

__device__ __forceinline__ f32x4 mfma32(short8 a, short8 b, f32x4 c) {
  return __builtin_amdgcn_mfma_f32_16x16x32_bf16(a, b, c, 0, 0, 0);
}

// ---------------- RMSNorm fp32 -> split bf16 (hi/lo) ----------------
__global__ __launch_bounds__(256) void rmsnorm_split_kernel(
    const float* __restrict__ x, const float* __restrict__ gamma,
    unsigned short* __restrict__ oh, unsigned short* __restrict__ ol) {
  int row = blockIdx.x, tid = threadIdx.x;
  const float* xr = x + (size_t)row * HD;
  float v[8];
#pragma unroll
  for (int i = 0; i < 8; ++i) v[i] = xr[tid * 8 + i];
  float ss = 0.f;
#pragma unroll
  for (int i = 0; i < 8; ++i) ss += v[i] * v[i];
#pragma unroll
  for (int off = 32; off; off >>= 1) ss += __shfl_xor(ss, off, 64);
  __shared__ float wss[4];
  if ((tid & 63) == 0) wss[tid >> 6] = ss;
  __syncthreads();
  float rs = rsqrtf((wss[0] + wss[1] + wss[2] + wss[3]) * (1.0f / HD) + 1e-5f);
  short8 vh, vl;
#pragma unroll
  for (int i = 0; i < 8; ++i) {
    float val = v[i] * rs * gamma[tid * 8 + i];
    unsigned short h, lo;
    split2(val, h, lo);
    vh[i] = (short)h;
    vl[i] = (short)lo;
  }
  *(short8*)(oh + (size_t)row * HD + tid * 8) = vh;
  *(short8*)(ol + (size_t)row * HD + tid * 8) = vl;
}

// ---------------- RMSNorm fp32 -> single bf16 (MoE input) ----------------
__global__ __launch_bounds__(256) void rmsnorm_plain_kernel(
    const float* __restrict__ x, const float* __restrict__ gamma,
    unsigned short* __restrict__ out) {
  int row = blockIdx.x, tid = threadIdx.x;
  const float* xr = x + (size_t)row * HD;
  float v[8];
#pragma unroll
  for (int i = 0; i < 8; ++i) v[i] = xr[tid * 8 + i];
  float ss = 0.f;
#pragma unroll
  for (int i = 0; i < 8; ++i) ss += v[i] * v[i];
#pragma unroll
  for (int off = 32; off; off >>= 1) ss += __shfl_xor(ss, off, 64);
  __shared__ float wss[4];
  if ((tid & 63) == 0) wss[tid >> 6] = ss;
  __syncthreads();
  float rs = rsqrtf((wss[0] + wss[1] + wss[2] + wss[3]) * (1.0f / HD) + 1e-5f);
  short8 o;
#pragma unroll
  for (int i = 0; i < 8; ++i) o[i] = (short)f2bf(v[i] * rs * gamma[tid * 8 + i]);
  *(short8*)(out + (size_t)row * HD + tid * 8) = o;
}

// ---------------- Split-precision GEMM, weight-stationary over 4 m-tiles -----
// acc = Ah*Wh + Ah*Wl + Al*Wh  (double-bf16, ~2^-17.5 relative)
// Block covers 256 rows (4 waves x 4 m-tiles of 16). Weights converted once
// per k-step, reused by 4 m-tiles -> weight HBM traffic = M/256 passes.
// MODE 0: split bf16 out [M,N]; MODE 1: split bf16 out transposed [N,M];
// MODE 2: fp32 out = val + resid -> outf and outf2.
template <int MODE>
__global__ __launch_bounds__(256) void gemm_split(
    const unsigned short* __restrict__ Ah, const unsigned short* __restrict__ Al,
    const float* __restrict__ W, const float* __restrict__ bias,
    const float* __restrict__ resid, unsigned short* __restrict__ outh,
    unsigned short* __restrict__ outl, float* __restrict__ outf,
    float* __restrict__ outf2, int M, int N, int Kd) {
  int l = threadIdx.x & 63, w = threadIdx.x >> 6;
  int g = l >> 4, q = l & 15;
  int n0 = blockIdx.x * 16;
  int n = n0 + q;
  int mbase = blockIdx.y * 256 + w * 64;
  const float* wp = W + (size_t)n * Kd + 8 * g;
  f32x4 acc[4] = {{0, 0, 0, 0}, {0, 0, 0, 0}, {0, 0, 0, 0}, {0, 0, 0, 0}};
  for (int k = 0; k < Kd; k += 32) {
    const float* wk = wp + k;
    short8 wh, wl;
#pragma unroll
    for (int j = 0; j < 8; ++j) {
      unsigned short h, lo;
      split2(wk[j], h, lo);
      wh[j] = (short)h;
      wl[j] = (short)lo;
    }
#pragma unroll
    for (int mt = 0; mt < 4; ++mt) {
      size_t aoff = (size_t)(mbase + mt * 16 + q) * Kd + 8 * g + k;
      short8 ah = *(const short8*)(Ah + aoff);
      short8 al = *(const short8*)(Al + aoff);
      acc[mt] = mfma32(ah, wh, acc[mt]);
      acc[mt] = mfma32(ah, wl, acc[mt]);
      acc[mt] = mfma32(al, wh, acc[mt]);
    }
  }
  float bs = bias[n];
#pragma unroll
  for (int mt = 0; mt < 4; ++mt) {
#pragma unroll
    for (int r = 0; r < 4; ++r) {
      int mr = mbase + mt * 16 + 4 * g + r;
      float val = acc[mt][r] + bs;
      if (MODE == 0) {
        unsigned short h, lo;
        split2(val, h, lo);
        outh[(size_t)mr * N + n] = h;
        outl[(size_t)mr * N + n] = lo;
      } else if (MODE == 1) {
        unsigned short h, lo;
        split2(val, h, lo);
        outh[(size_t)n * M + mr] = h;
        outl[(size_t)n * M + mr] = lo;
      } else {
        float vv = val + resid[(size_t)mr * N + n];
        outf[(size_t)mr * N + n] = vv;
        outf2[(size_t)mr * N + n] = vv;
      }
    }
  }
}

// ---------------- Flash attention with sink, split precision ----------------
__global__ __launch_bounds__(256) void attn_kernel(
    const unsigned short* __restrict__ Qh, const unsigned short* __restrict__ Ql,
    const unsigned short* __restrict__ Kh, const unsigned short* __restrict__ Kl,
    const unsigned short* __restrict__ Vh, const unsigned short* __restrict__ Vl,
    const float* __restrict__ sinks, unsigned short* __restrict__ outh,
    unsigned short* __restrict__ outl) {
  // P staged through LDS row-major [q][32 keys] so both PV operands use the
  // standard contiguous-8 load pattern (fragment k-mapping cancels).
  __shared__ __align__(16) unsigned short pbuf[4][2][16][40];
  int l = threadIdx.x & 63, widx = threadIdx.x >> 6;
  int wid = blockIdx.x * 4 + widx;
  int head = wid >> 6, qt = wid & 63;
  int q0 = qt * 16;
  int g = l >> 4, q = l & 15;
  int kvh = head >> 2;
  size_t qoff = (size_t)(q0 + q) * (NHEAD * DHEAD) + head * DHEAD + 8 * g;
  short8 qh0 = *(const short8*)(Qh + qoff);
  short8 qh1 = *(const short8*)(Qh + qoff + 32);
  short8 ql0 = *(const short8*)(Ql + qoff);
  short8 ql1 = *(const short8*)(Ql + qoff + 32);
  float m = sinks[head];  // online softmax init: sink contributes exp(0)=1
  float lsum = 1.0f;
  f32x4 o[4] = {{0, 0, 0, 0}, {0, 0, 0, 0}, {0, 0, 0, 0}, {0, 0, 0, 0}};
  int qglob = q0 + q;
  for (int kt = 0; kt <= qt; kt += 2) {
    bool hasB = (kt + 1) <= qt;
    size_t koff = (size_t)(kt * 16 + q) * (NKVH * DHEAD) + kvh * DHEAD + 8 * g;
    f32x4 stA = {0, 0, 0, 0};
    {
      short8 kh0 = *(const short8*)(Kh + koff);
      short8 kh1 = *(const short8*)(Kh + koff + 32);
      short8 kl0 = *(const short8*)(Kl + koff);
      short8 kl1 = *(const short8*)(Kl + koff + 32);
      stA = mfma32(kh0, qh0, stA);
      stA = mfma32(kh0, ql0, stA);
      stA = mfma32(kl0, qh0, stA);
      stA = mfma32(kh1, qh1, stA);
      stA = mfma32(kh1, ql1, stA);
      stA = mfma32(kl1, qh1, stA);
    }
    f32x4 stB = {0, 0, 0, 0};
    if (hasB) {
      size_t koff2 = koff + (size_t)16 * (NKVH * DHEAD);
      short8 kh0 = *(const short8*)(Kh + koff2);
      short8 kh1 = *(const short8*)(Kh + koff2 + 32);
      short8 kl0 = *(const short8*)(Kl + koff2);
      short8 kl1 = *(const short8*)(Kl + koff2 + 32);
      stB = mfma32(kh0, qh0, stB);
      stB = mfma32(kh0, ql0, stB);
      stB = mfma32(kl0, qh0, stB);
      stB = mfma32(kh1, qh1, stB);
      stB = mfma32(kh1, ql1, stB);
      stB = mfma32(kl1, qh1, stB);
    }
    float sA[4], sB[4];
#pragma unroll
    for (int r = 0; r < 4; ++r) {
      int keyA = kt * 16 + 4 * g + r;
      sA[r] = (keyA <= qglob) ? stA[r] * SCALE : -1e30f;
      sB[r] = (hasB && keyA + 16 <= qglob) ? stB[r] * SCALE : -1e30f;
    }
    float mt = fmaxf(fmaxf(fmaxf(sA[0], sA[1]), fmaxf(sA[2], sA[3])),
                     fmaxf(fmaxf(sB[0], sB[1]), fmaxf(sB[2], sB[3])));
    mt = fmaxf(mt, __shfl_xor(mt, 16, 64));
    mt = fmaxf(mt, __shfl_xor(mt, 32, 64));
    float mnew = fmaxf(m, mt);
    float corr = __expf(m - mnew);
    float pA[4], pB[4];
    float rsum = 0.f;
#pragma unroll
    for (int r = 0; r < 4; ++r) {
      pA[r] = __expf(sA[r] - mnew);
      pB[r] = __expf(sB[r] - mnew);
      rsum += pA[r] + pB[r];
    }
    rsum += __shfl_xor(rsum, 16, 64);
    rsum += __shfl_xor(rsum, 32, 64);
    lsum = lsum * corr + rsum;
    m = mnew;
#pragma unroll
    for (int dt = 0; dt < 4; ++dt)
#pragma unroll
      for (int r = 0; r < 4; ++r) o[dt][r] *= corr;
    // split P and stage via LDS: row q, cols = key offsets in [0,32)
    unsigned short ph[8], pl[8];
#pragma unroll
    for (int r = 0; r < 4; ++r) {
      split2(pA[r], ph[r], pl[r]);
      split2(pB[r], ph[4 + r], pl[4 + r]);
    }
    short4v wAh = {(short)ph[0], (short)ph[1], (short)ph[2], (short)ph[3]};
    short4v wBh = {(short)ph[4], (short)ph[5], (short)ph[6], (short)ph[7]};
    short4v wAl = {(short)pl[0], (short)pl[1], (short)pl[2], (short)pl[3]};
    short4v wBl = {(short)pl[4], (short)pl[5], (short)pl[6], (short)pl[7]};
    *(short4v*)&pbuf[widx][0][q][4 * g] = wAh;       // tile-A keys 4g..4g+3
    *(short4v*)&pbuf[widx][0][q][16 + 4 * g] = wBh;  // tile-B keys
    *(short4v*)&pbuf[widx][1][q][4 * g] = wAl;
    *(short4v*)&pbuf[widx][1][q][16 + 4 * g] = wBl;
    asm volatile("s_waitcnt lgkmcnt(0)" ::: "memory");
    short8 pbh = *(const short8*)&pbuf[widx][0][q][8 * g];
    short8 pbl = *(const short8*)&pbuf[widx][1][q][8 * g];
    size_t vbase = (size_t)(kvh * DHEAD) * SEQ + kt * 16 + 8 * g;
#pragma unroll
    for (int dt = 0; dt < 4; ++dt) {
      size_t voff = vbase + (size_t)(dt * 16 + q) * SEQ;
      short8 vh8 = *(const short8*)(Vh + voff);
      short8 vl8 = *(const short8*)(Vl + voff);
      o[dt] = mfma32(vh8, pbh, o[dt]);
      o[dt] = mfma32(vh8, pbl, o[dt]);
      o[dt] = mfma32(vl8, pbh, o[dt]);
    }
  }
  float inv = 1.0f / lsum;
#pragma unroll
  for (int dt = 0; dt < 4; ++dt)
#pragma unroll
    for (int r = 0; r < 4; ++r) {
      float val = o[dt][r] * inv;
      unsigned short h, lo;
      split2(val, h, lo);
      size_t idx = (size_t)qglob * (NHEAD * DHEAD) + head * DHEAD + dt * 16 + 4 * g + r;
      outh[idx] = h;
      outl[idx] = lo;
    }
}

// ---------------- Router: fp64 norm + logits, top-2, build expert lists ------
__global__ __launch_bounds__(64) void router_kernel(
    const float* __restrict__ h, const float* __restrict__ gamma,
    const float* __restrict__ rw, const float* __restrict__ rb,
    float* __restrict__ wts, int* __restrict__ counts, int* __restrict__ lists) {
  int t = blockIdx.x;
  int l = threadIdx.x;
  const float* hr = h + (size_t)t * HD;
  double ss = 0.0;
  for (int i = l; i < HD; i += 64) {
    double x = (double)hr[i];
    ss += x * x;
  }
#pragma unroll
  for (int off = 32; off; off >>= 1) ss += __shfl_xor(ss, off, 64);
  double rs = rsqrt(ss * (1.0 / HD) + 1e-5);
  double acc[NEXP];
#pragma unroll
  for (int e = 0; e < NEXP; ++e) acc[e] = 0.0;
  for (int i = l; i < HD; i += 64) {
    double xh = (double)hr[i] * rs * (double)gamma[i];
#pragma unroll
    for (int e = 0; e < NEXP; ++e) acc[e] += xh * (double)rw[e * HD + i];
  }
#pragma unroll
  for (int e = 0; e < NEXP; ++e)
#pragma unroll
    for (int off = 32; off; off >>= 1) acc[e] += __shfl_xor(acc[e], off, 64);
  if (l == 0) {
    double lg[NEXP];
#pragma unroll
    for (int e = 0; e < NEXP; ++e) lg[e] = acc[e] + (double)rb[e];
    int e0 = 0;
#pragma unroll
    for (int e = 1; e < NEXP; ++e)
      if (lg[e] > lg[e0]) e0 = e;
    int e1 = -1;
#pragma unroll
    for (int e = 0; e < NEXP; ++e)
      if (e != e0 && (e1 < 0 || lg[e] > lg[e1])) e1 = e;
    double d = exp(lg[e1] - lg[e0]);
    float p0 = (float)(1.0 / (1.0 + d)), p1 = (float)(d / (1.0 + d));
#pragma unroll
    for (int e = 0; e < NEXP; ++e)
      wts[t * NEXP + e] = (e == e0) ? p0 : (e == e1) ? p1 : 0.f;
    int s0 = atomicAdd(&counts[e0], 1);
    lists[e0 * SEQ + s0] = t;
    int s1 = atomicAdd(&counts[e1], 1);
    lists[e1 * SEQ + s1] = t;
  }
}

// ------ MoE gate/up grouped GEMM, weight-stationary over 4 m-tiles ----------
__global__ __launch_bounds__(256) void gemm_gateup(
    const unsigned short* __restrict__ hn, const float* __restrict__ Wg,
    const float* __restrict__ bg, const float* __restrict__ Wu,
    const float* __restrict__ bu, const int* __restrict__ counts,
    const int* __restrict__ lists, unsigned short* __restrict__ gated) {
  int e = blockIdx.z;
  int count = counts[e];
  int l = threadIdx.x & 63, w = threadIdx.x >> 6;
  int g = l >> 4, q = l & 15;
  int n0 = blockIdx.x * 16;
  int n = n0 + q;
  const float* wgp = Wg + ((size_t)e * INTER + n) * HD + 8 * g;
  const float* wup = Wu + ((size_t)e * INTER + n) * HD + 8 * g;
  float bgs = bg[e * INTER + n], bus = bu[e * INTER + n];
  for (int mg = 0; mg * 256 < count; ++mg) {
    int mbase = mg * 256 + w * 64;
    const unsigned short* ap[4];
#pragma unroll
    for (int mt = 0; mt < 4; ++mt) {
      int tok = lists[e * SEQ + min(mbase + mt * 16 + q, count - 1)];
      ap[mt] = hn + (size_t)tok * HD + 8 * g;
    }
    f32x4 ag[4] = {{0, 0, 0, 0}, {0, 0, 0, 0}, {0, 0, 0, 0}, {0, 0, 0, 0}};
    f32x4 au[4] = {{0, 0, 0, 0}, {0, 0, 0, 0}, {0, 0, 0, 0}, {0, 0, 0, 0}};
    for (int k = 0; k < HD; k += 32) {
      const float* wg = wgp + k;
      const float* wu = wup + k;
      short8 bgf, buf;
#pragma unroll
      for (int j = 0; j < 8; ++j) {
        bgf[j] = (short)f2bf(wg[j]);
        buf[j] = (short)f2bf(wu[j]);
      }
#pragma unroll
      for (int mt = 0; mt < 4; ++mt) {
        short8 a = *(const short8*)(ap[mt] + k);
        ag[mt] = mfma32(a, bgf, ag[mt]);
        au[mt] = mfma32(a, buf, au[mt]);
      }
    }
#pragma unroll
    for (int mt = 0; mt < 4; ++mt) {
#pragma unroll
      for (int r = 0; r < 4; ++r) {
        int mm = mbase + mt * 16 + 4 * g + r;
        if (mm < count) {
          float gate = ag[mt][r] + bgs, up = au[mt][r] + bus;
          float gc = fminf(gate, LIMIT);
          float uc = fminf(fmaxf(up, -LIMIT), LIMIT);
          float glu = gc / (1.f + __expf(-ALPHA * gc));
          gated[((size_t)e * SEQ + mm) * INTER + n] = f2bf((uc + 1.f) * glu);
        }
      }
    }
  }
}

// ------ MoE down grouped GEMM, weight-stationary over 4 m-tiles -------------
__global__ __launch_bounds__(256) void gemm_down(
    const unsigned short* __restrict__ gated, const float* __restrict__ Wd,
    const float* __restrict__ bd, const int* __restrict__ counts,
    const int* __restrict__ lists, const float* __restrict__ wts,
    float* __restrict__ out) {
  int e = blockIdx.z;
  int count = counts[e];
  int l = threadIdx.x & 63, w = threadIdx.x >> 6;
  int g = l >> 4, q = l & 15;
  int n0 = blockIdx.x * 16;
  int n = n0 + q;
  const float* wp = Wd + ((size_t)e * HD + n) * INTER + 8 * g;
  float bds = bd[e * HD + n];
  for (int mg = 0; mg * 256 < count; ++mg) {
    int mbase = mg * 256 + w * 64;
    const unsigned short* ap[4];
#pragma unroll
    for (int mt = 0; mt < 4; ++mt) {
      ap[mt] = gated + ((size_t)e * SEQ + min(mbase + mt * 16 + q, count - 1)) * INTER + 8 * g;
    }
    f32x4 acc[4] = {{0, 0, 0, 0}, {0, 0, 0, 0}, {0, 0, 0, 0}, {0, 0, 0, 0}};
    for (int k = 0; k < INTER; k += 32) {
      const float* wk = wp + k;
      short8 b;
#pragma unroll
      for (int j = 0; j < 8; ++j) b[j] = (short)f2bf(wk[j]);
#pragma unroll
      for (int mt = 0; mt < 4; ++mt) {
        short8 a = *(const short8*)(ap[mt] + k);
        acc[mt] = mfma32(a, b, acc[mt]);
      }
    }
#pragma unroll
    for (int mt = 0; mt < 4; ++mt) {
#pragma unroll
      for (int r = 0; r < 4; ++r) {
        int mm = mbase + mt * 16 + 4 * g + r;
        if (mm < count) {
          int t = lists[e * SEQ + mm];
          float wt = wts[t * NEXP + e];
          atomicAdd(&out[(size_t)t * HD + n], (acc[mt][r] + bds) * wt);
        }
      }
    }
  }
}

extern "C" void kernel_launch(void* const* d_in, const int* in_sizes, int n_in,
                              void* d_out, int out_size, void* d_ws,
                              size_t ws_size, hipStream_t stream) {
  const float* x = (const float*)d_in[0];
  const float* ln1 = (const float*)d_in[2];
  const float* ln2 = (const float*)d_in[3];
  const float* Wq = (const float*)d_in[4];
  const float* bq = (const float*)d_in[5];
  const float* Wk = (const float*)d_in[6];
  const float* bk = (const float*)d_in[7];
  const float* Wv = (const float*)d_in[8];
  const float* bv = (const float*)d_in[9];
  const float* Wo = (const float*)d_in[10];
  const float* bo = (const float*)d_in[11];
  const float* sinks = (const float*)d_in[12];
  const float* rw = (const float*)d_in[13];
  const float* rb = (const float*)d_in[14];
  const float* Wg = (const float*)d_in[15];
  const float* bg = (const float*)d_in[16];
  const float* Wu = (const float*)d_in[17];
  const float* bu = (const float*)d_in[18];
  const float* Wd = (const float*)d_in[19];
  const float* bd = (const float*)d_in[20];
  float* out = (float*)d_out;

  char* ws = (char*)d_ws;
  size_t off = 0;
  auto alloc = [&](size_t bytes) {
    void* p = ws + off;
    off += (bytes + 255) & ~(size_t)255;
    return p;
  };
  unsigned short* xnh = (unsigned short*)alloc((size_t)SEQ * HD * 2);
  unsigned short* xnl = (unsigned short*)alloc((size_t)SEQ * HD * 2);
  unsigned short* qbh = (unsigned short*)alloc((size_t)SEQ * NHEAD * DHEAD * 2);
  unsigned short* qbl = (unsigned short*)alloc((size_t)SEQ * NHEAD * DHEAD * 2);
  unsigned short* kbh = (unsigned short*)alloc((size_t)SEQ * NKVH * DHEAD * 2);
  unsigned short* kbl = (unsigned short*)alloc((size_t)SEQ * NKVH * DHEAD * 2);
  unsigned short* vth = (unsigned short*)alloc((size_t)NKVH * DHEAD * SEQ * 2);
  unsigned short* vtl = (unsigned short*)alloc((size_t)NKVH * DHEAD * SEQ * 2);
  unsigned short* ath = (unsigned short*)alloc((size_t)SEQ * NHEAD * DHEAD * 2);
  unsigned short* atl = (unsigned short*)alloc((size_t)SEQ * NHEAD * DHEAD * 2);
  float* hbuf = (float*)alloc((size_t)SEQ * HD * 4);
  unsigned short* hn = (unsigned short*)alloc((size_t)SEQ * HD * 2);
  float* wts = (float*)alloc((size_t)SEQ * NEXP * 4);
  int* counts = (int*)alloc(NEXP * 4);
  int* lists = (int*)alloc((size_t)NEXP * SEQ * 4);
  unsigned short* gated = (unsigned short*)alloc((size_t)NEXP * SEQ * INTER * 2);
  (void)ws_size;
  (void)off;

  rmsnorm_split_kernel<<<SEQ, 256, 0, stream>>>(x, ln1, xnh, xnl);
  gemm_split<0><<<dim3(NHEAD * DHEAD / 16, SEQ / 256), 256, 0, stream>>>(
      xnh, xnl, Wq, bq, nullptr, qbh, qbl, nullptr, nullptr, SEQ, NHEAD * DHEAD, HD);
  gemm_split<0><<<dim3(NKVH * DHEAD / 16, SEQ / 256), 256, 0, stream>>>(
      xnh, xnl, Wk, bk, nullptr, kbh, kbl, nullptr, nullptr, SEQ, NKVH * DHEAD, HD);
  gemm_split<1><<<dim3(NKVH * DHEAD / 16, SEQ / 256), 256, 0, stream>>>(
      xnh, xnl, Wv, bv, nullptr, vth, vtl, nullptr, nullptr, SEQ, NKVH * DHEAD, HD);
  attn_kernel<<<NHEAD * 64 / 4, 256, 0, stream>>>(qbh, qbl, kbh, kbl, vth, vtl,
                                                  sinks, ath, atl);
  gemm_split<2><<<dim3(HD / 16, SEQ / 256), 256, 0, stream>>>(
      ath, atl, Wo, bo, x, nullptr, nullptr, hbuf, out, SEQ, HD, NHEAD * DHEAD);
  rmsnorm_plain_kernel<<<SEQ, 256, 0, stream>>>(hbuf, ln2, hn);
  hipMemsetAsync(counts, 0, NEXP * sizeof(int), stream);
  router_kernel<<<SEQ, 64, 0, stream>>>(hbuf, ln2, rw, rb, wts, counts, lists);
  gemm_gateup<<<dim3(INTER / 16, 1, NEXP), 256, 0, stream>>>(
      hn, Wg, bg, Wu, bu, counts, lists, gated);
  gemm_down<<<dim3(HD / 16, 1, NEXP), 256, 0, stream>>>(
      gated, Wd, bd, counts, lists, wts, out);
}

// Round 4
// 940.624 us; speedup vs baseline: 1.8892x; 1.3601x over previous
//
#include <hip/hip_runtime.h>
#include <hip/hip_bf16.h>

#define HD 2048
#define SEQ 1024
#define NHEAD 32
#define NKVH 8
#define DHEAD 64
#define NEXP 8
#define INTER 2048
#define SCALE 0.125f
#define ALPHA 1.702f
#define LIMIT 7.0f

typedef __attribute__((ext_vector_type(8))) short short8;
typedef __attribute__((ext_vector_type(4))) short short4v;
typedef __attribute__((ext_vector_type(4))) float f32x4;

__device__ __forceinline__ unsigned short f2bf(float f) {
  union { float f; unsigned u; } v; v.f = f;
  unsigned r = v.u + 0x7fffu + ((v.u >> 16) & 1u);
  return (unsigned short)(r >> 16);
}
__device__ __forceinline__ float bf2f(unsigned short h) {
  union { unsigned u; float f; } v; v.u = ((unsigned)h) << 16; return v.f;
}
__device__ __forceinline__ void split2(float f, unsigned short& hi, unsigned short& lo) {
  hi = f2bf(f);
  lo = f2bf(f - bf2f(hi));
}

__device__ __forceinline__ f32x4 mfma32(short8 a, short8 b, f32x4 c) {
  return __builtin_amdgcn_mfma_f32_16x16x32_bf16(a, b, c, 0, 0, 0);
}

// ---------------- RMSNorm fp32 -> split bf16 (hi/lo) ----------------
__global__ __launch_bounds__(256) void rmsnorm_split_kernel(
    const float* __restrict__ x, const float* __restrict__ gamma,
    unsigned short* __restrict__ oh, unsigned short* __restrict__ ol) {
  int row = blockIdx.x, tid = threadIdx.x;
  const float* xr = x + (size_t)row * HD;
  float v[8];
#pragma unroll
  for (int i = 0; i < 8; ++i) v[i] = xr[tid * 8 + i];
  float ss = 0.f;
#pragma unroll
  for (int i = 0; i < 8; ++i) ss += v[i] * v[i];
#pragma unroll
  for (int off = 32; off; off >>= 1) ss += __shfl_xor(ss, off, 64);
  __shared__ float wss[4];
  if ((tid & 63) == 0) wss[tid >> 6] = ss;
  __syncthreads();
  float rs = rsqrtf((wss[0] + wss[1] + wss[2] + wss[3]) * (1.0f / HD) + 1e-5f);
  short8 vh, vl;
#pragma unroll
  for (int i = 0; i < 8; ++i) {
    float val = v[i] * rs * gamma[tid * 8 + i];
    unsigned short h, lo;
    split2(val, h, lo);
    vh[i] = (short)h;
    vl[i] = (short)lo;
  }
  *(short8*)(oh + (size_t)row * HD + tid * 8) = vh;
  *(short8*)(ol + (size_t)row * HD + tid * 8) = vl;
}

// ---------------- RMSNorm fp32 -> single bf16 (MoE input) ----------------
__global__ __launch_bounds__(256) void rmsnorm_plain_kernel(
    const float* __restrict__ x, const float* __restrict__ gamma,
    unsigned short* __restrict__ out) {
  int row = blockIdx.x, tid = threadIdx.x;
  const float* xr = x + (size_t)row * HD;
  float v[8];
#pragma unroll
  for (int i = 0; i < 8; ++i) v[i] = xr[tid * 8 + i];
  float ss = 0.f;
#pragma unroll
  for (int i = 0; i < 8; ++i) ss += v[i] * v[i];
#pragma unroll
  for (int off = 32; off; off >>= 1) ss += __shfl_xor(ss, off, 64);
  __shared__ float wss[4];
  if ((tid & 63) == 0) wss[tid >> 6] = ss;
  __syncthreads();
  float rs = rsqrtf((wss[0] + wss[1] + wss[2] + wss[3]) * (1.0f / HD) + 1e-5f);
  short8 o;
#pragma unroll
  for (int i = 0; i < 8; ++i) o[i] = (short)f2bf(v[i] * rs * gamma[tid * 8 + i]);
  *(short8*)(out + (size_t)row * HD + tid * 8) = o;
}

// ---------------- Split-precision GEMM, LDS-staged weights -------------------
// acc = Ah*Wh + Ah*Wl + Al*Wh  (double-bf16). Block: 16 n-cols x 256 m-rows.
// Per 128-k-chunk: 256 threads cooperatively load+split the 16x128 fp32 weight
// tile into LDS (converted once, not once per wave). Padded rows (136 elems =
// 272B) spread ds_read_b128 across all 32 banks.
// MODE 0: split bf16 out [M,N]; MODE 1: split bf16 out transposed [N,M];
// MODE 2: fp32 out = val + resid -> outf and outf2.
template <int MODE>
__global__ __launch_bounds__(256) void gemm_split(
    const unsigned short* __restrict__ Ah, const unsigned short* __restrict__ Al,
    const float* __restrict__ W, const float* __restrict__ bias,
    const float* __restrict__ resid, unsigned short* __restrict__ outh,
    unsigned short* __restrict__ outl, float* __restrict__ outf,
    float* __restrict__ outf2, int M, int N, int Kd) {
  __shared__ __align__(16) unsigned short lwh[16][136];
  __shared__ __align__(16) unsigned short lwl[16][136];
  int tid = threadIdx.x;
  int l = tid & 63, w = tid >> 6;
  int g = l >> 4, q = l & 15;
  int n0 = blockIdx.x * 16;
  int n = n0 + q;
  int mbase = blockIdx.y * 256 + w * 64;
  int srow = tid >> 4, scol = (tid & 15) * 8;
  const float* wsp = W + (size_t)(n0 + srow) * Kd + scol;
  f32x4 acc[4] = {{0, 0, 0, 0}, {0, 0, 0, 0}, {0, 0, 0, 0}, {0, 0, 0, 0}};
  float4 w0 = *(const float4*)(wsp);
  float4 w1 = *(const float4*)(wsp + 4);
  for (int kc = 0; kc < Kd; kc += 128) {
    __syncthreads();
    {
      float wv[8] = {w0.x, w0.y, w0.z, w0.w, w1.x, w1.y, w1.z, w1.w};
      short8 hh, ll;
#pragma unroll
      for (int j = 0; j < 8; ++j) {
        unsigned short h, lo;
        split2(wv[j], h, lo);
        hh[j] = (short)h;
        ll[j] = (short)lo;
      }
      *(short8*)&lwh[srow][scol] = hh;
      *(short8*)&lwl[srow][scol] = ll;
    }
    __syncthreads();
    if (kc + 128 < Kd) {
      w0 = *(const float4*)(wsp + kc + 128);
      w1 = *(const float4*)(wsp + kc + 128 + 4);
    }
#pragma unroll
    for (int kh = 0; kh < 4; ++kh) {
      short8 wh = *(const short8*)&lwh[q][kh * 32 + 8 * g];
      short8 wl = *(const short8*)&lwl[q][kh * 32 + 8 * g];
#pragma unroll
      for (int mt = 0; mt < 4; ++mt) {
        size_t aoff = (size_t)(mbase + mt * 16 + q) * Kd + kc + kh * 32 + 8 * g;
        short8 ah = *(const short8*)(Ah + aoff);
        short8 al = *(const short8*)(Al + aoff);
        acc[mt] = mfma32(ah, wh, acc[mt]);
        acc[mt] = mfma32(ah, wl, acc[mt]);
        acc[mt] = mfma32(al, wh, acc[mt]);
      }
    }
  }
  float bs = bias[n];
#pragma unroll
  for (int mt = 0; mt < 4; ++mt) {
#pragma unroll
    for (int r = 0; r < 4; ++r) {
      int mr = mbase + mt * 16 + 4 * g + r;
      float val = acc[mt][r] + bs;
      if (MODE == 0) {
        unsigned short h, lo;
        split2(val, h, lo);
        outh[(size_t)mr * N + n] = h;
        outl[(size_t)mr * N + n] = lo;
      } else if (MODE == 1) {
        unsigned short h, lo;
        split2(val, h, lo);
        outh[(size_t)n * M + mr] = h;
        outl[(size_t)n * M + mr] = lo;
      } else {
        float vv = val + resid[(size_t)mr * N + n];
        outf[(size_t)mr * N + n] = vv;
        outf2[(size_t)mr * N + n] = vv;
      }
    }
  }
}

// ---------------- Flash attention with sink, split precision ----------------
__global__ __launch_bounds__(256) void attn_kernel(
    const unsigned short* __restrict__ Qh, const unsigned short* __restrict__ Ql,
    const unsigned short* __restrict__ Kh, const unsigned short* __restrict__ Kl,
    const unsigned short* __restrict__ Vh, const unsigned short* __restrict__ Vl,
    const float* __restrict__ sinks, unsigned short* __restrict__ outh,
    unsigned short* __restrict__ outl) {
  // P staged through LDS row-major [q][32 keys] so both PV operands use the
  // standard contiguous-8 load pattern (fragment k-mapping cancels).
  __shared__ __align__(16) unsigned short pbuf[4][2][16][40];
  int l = threadIdx.x & 63, widx = threadIdx.x >> 6;
  int wid = blockIdx.x * 4 + widx;
  int head = wid >> 6, qt = wid & 63;
  int q0 = qt * 16;
  int g = l >> 4, q = l & 15;
  int kvh = head >> 2;
  size_t qoff = (size_t)(q0 + q) * (NHEAD * DHEAD) + head * DHEAD + 8 * g;
  short8 qh0 = *(const short8*)(Qh + qoff);
  short8 qh1 = *(const short8*)(Qh + qoff + 32);
  short8 ql0 = *(const short8*)(Ql + qoff);
  short8 ql1 = *(const short8*)(Ql + qoff + 32);
  float m = sinks[head];  // online softmax init: sink contributes exp(0)=1
  float lsum = 1.0f;
  f32x4 o[4] = {{0, 0, 0, 0}, {0, 0, 0, 0}, {0, 0, 0, 0}, {0, 0, 0, 0}};
  int qglob = q0 + q;
  for (int kt = 0; kt <= qt; kt += 2) {
    bool hasB = (kt + 1) <= qt;
    size_t koff = (size_t)(kt * 16 + q) * (NKVH * DHEAD) + kvh * DHEAD + 8 * g;
    f32x4 stA = {0, 0, 0, 0};
    {
      short8 kh0 = *(const short8*)(Kh + koff);
      short8 kh1 = *(const short8*)(Kh + koff + 32);
      short8 kl0 = *(const short8*)(Kl + koff);
      short8 kl1 = *(const short8*)(Kl + koff + 32);
      stA = mfma32(kh0, qh0, stA);
      stA = mfma32(kh0, ql0, stA);
      stA = mfma32(kl0, qh0, stA);
      stA = mfma32(kh1, qh1, stA);
      stA = mfma32(kh1, ql1, stA);
      stA = mfma32(kl1, qh1, stA);
    }
    f32x4 stB = {0, 0, 0, 0};
    if (hasB) {
      size_t koff2 = koff + (size_t)16 * (NKVH * DHEAD);
      short8 kh0 = *(const short8*)(Kh + koff2);
      short8 kh1 = *(const short8*)(Kh + koff2 + 32);
      short8 kl0 = *(const short8*)(Kl + koff2);
      short8 kl1 = *(const short8*)(Kl + koff2 + 32);
      stB = mfma32(kh0, qh0, stB);
      stB = mfma32(kh0, ql0, stB);
      stB = mfma32(kl0, qh0, stB);
      stB = mfma32(kh1, qh1, stB);
      stB = mfma32(kh1, ql1, stB);
      stB = mfma32(kl1, qh1, stB);
    }
    float sA[4], sB[4];
#pragma unroll
    for (int r = 0; r < 4; ++r) {
      int keyA = kt * 16 + 4 * g + r;
      sA[r] = (keyA <= qglob) ? stA[r] * SCALE : -1e30f;
      sB[r] = (hasB && keyA + 16 <= qglob) ? stB[r] * SCALE : -1e30f;
    }
    float mt = fmaxf(fmaxf(fmaxf(sA[0], sA[1]), fmaxf(sA[2], sA[3])),
                     fmaxf(fmaxf(sB[0], sB[1]), fmaxf(sB[2], sB[3])));
    mt = fmaxf(mt, __shfl_xor(mt, 16, 64));
    mt = fmaxf(mt, __shfl_xor(mt, 32, 64));
    float mnew = fmaxf(m, mt);
    float corr = __expf(m - mnew);
    float pA[4], pB[4];
    float rsum = 0.f;
#pragma unroll
    for (int r = 0; r < 4; ++r) {
      pA[r] = __expf(sA[r] - mnew);
      pB[r] = __expf(sB[r] - mnew);
      rsum += pA[r] + pB[r];
    }
    rsum += __shfl_xor(rsum, 16, 64);
    rsum += __shfl_xor(rsum, 32, 64);
    lsum = lsum * corr + rsum;
    m = mnew;
#pragma unroll
    for (int dt = 0; dt < 4; ++dt)
#pragma unroll
      for (int r = 0; r < 4; ++r) o[dt][r] *= corr;
    // split P and stage via LDS: row q, cols = key offsets in [0,32)
    unsigned short ph[8], pl[8];
#pragma unroll
    for (int r = 0; r < 4; ++r) {
      split2(pA[r], ph[r], pl[r]);
      split2(pB[r], ph[4 + r], pl[4 + r]);
    }
    short4v wAh = {(short)ph[0], (short)ph[1], (short)ph[2], (short)ph[3]};
    short4v wBh = {(short)ph[4], (short)ph[5], (short)ph[6], (short)ph[7]};
    short4v wAl = {(short)pl[0], (short)pl[1], (short)pl[2], (short)pl[3]};
    short4v wBl = {(short)pl[4], (short)pl[5], (short)pl[6], (short)pl[7]};
    *(short4v*)&pbuf[widx][0][q][4 * g] = wAh;       // tile-A keys 4g..4g+3
    *(short4v*)&pbuf[widx][0][q][16 + 4 * g] = wBh;  // tile-B keys
    *(short4v*)&pbuf[widx][1][q][4 * g] = wAl;
    *(short4v*)&pbuf[widx][1][q][16 + 4 * g] = wBl;
    asm volatile("s_waitcnt lgkmcnt(0)" ::: "memory");
    short8 pbh = *(const short8*)&pbuf[widx][0][q][8 * g];
    short8 pbl = *(const short8*)&pbuf[widx][1][q][8 * g];
    size_t vbase = (size_t)(kvh * DHEAD) * SEQ + kt * 16 + 8 * g;
#pragma unroll
    for (int dt = 0; dt < 4; ++dt) {
      size_t voff = vbase + (size_t)(dt * 16 + q) * SEQ;
      short8 vh8 = *(const short8*)(Vh + voff);
      short8 vl8 = *(const short8*)(Vl + voff);
      o[dt] = mfma32(vh8, pbh, o[dt]);
      o[dt] = mfma32(vh8, pbl, o[dt]);
      o[dt] = mfma32(vl8, pbh, o[dt]);
    }
  }
  float inv = 1.0f / lsum;
#pragma unroll
  for (int dt = 0; dt < 4; ++dt)
#pragma unroll
    for (int r = 0; r < 4; ++r) {
      float val = o[dt][r] * inv;
      unsigned short h, lo;
      split2(val, h, lo);
      size_t idx = (size_t)qglob * (NHEAD * DHEAD) + head * DHEAD + dt * 16 + 4 * g + r;
      outh[idx] = h;
      outl[idx] = lo;
    }
}

// ---------------- Router: fp64 norm + logits, top-2, build expert lists ------
__global__ __launch_bounds__(64) void router_kernel(
    const float* __restrict__ h, const float* __restrict__ gamma,
    const float* __restrict__ rw, const float* __restrict__ rb,
    float* __restrict__ wts, int* __restrict__ counts, int* __restrict__ lists) {
  int t = blockIdx.x;
  int l = threadIdx.x;
  const float* hr = h + (size_t)t * HD;
  double ss = 0.0;
  for (int i = l; i < HD; i += 64) {
    double x = (double)hr[i];
    ss += x * x;
  }
#pragma unroll
  for (int off = 32; off; off >>= 1) ss += __shfl_xor(ss, off, 64);
  double rs = rsqrt(ss * (1.0 / HD) + 1e-5);
  double acc[NEXP];
#pragma unroll
  for (int e = 0; e < NEXP; ++e) acc[e] = 0.0;
  for (int i = l; i < HD; i += 64) {
    double xh = (double)hr[i] * rs * (double)gamma[i];
#pragma unroll
    for (int e = 0; e < NEXP; ++e) acc[e] += xh * (double)rw[e * HD + i];
  }
#pragma unroll
  for (int e = 0; e < NEXP; ++e)
#pragma unroll
    for (int off = 32; off; off >>= 1) acc[e] += __shfl_xor(acc[e], off, 64);
  if (l == 0) {
    double lg[NEXP];
#pragma unroll
    for (int e = 0; e < NEXP; ++e) lg[e] = acc[e] + (double)rb[e];
    int e0 = 0;
#pragma unroll
    for (int e = 1; e < NEXP; ++e)
      if (lg[e] > lg[e0]) e0 = e;
    int e1 = -1;
#pragma unroll
    for (int e = 0; e < NEXP; ++e)
      if (e != e0 && (e1 < 0 || lg[e] > lg[e1])) e1 = e;
    double d = exp(lg[e1] - lg[e0]);
    float p0 = (float)(1.0 / (1.0 + d)), p1 = (float)(d / (1.0 + d));
#pragma unroll
    for (int e = 0; e < NEXP; ++e)
      wts[t * NEXP + e] = (e == e0) ? p0 : (e == e1) ? p1 : 0.f;
    int s0 = atomicAdd(&counts[e0], 1);
    lists[e0 * SEQ + s0] = t;
    int s1 = atomicAdd(&counts[e1], 1);
    lists[e1 * SEQ + s1] = t;
  }
}

// ------ MoE gate/up grouped GEMM, LDS-staged weights ------------------------
__global__ __launch_bounds__(256) void gemm_gateup(
    const unsigned short* __restrict__ hn, const float* __restrict__ Wg,
    const float* __restrict__ bg, const float* __restrict__ Wu,
    const float* __restrict__ bu, const int* __restrict__ counts,
    const int* __restrict__ lists, unsigned short* __restrict__ gated) {
  __shared__ __align__(16) unsigned short lwg[16][136];
  __shared__ __align__(16) unsigned short lwu[16][136];
  int e = blockIdx.z;
  int count = counts[e];
  int tid = threadIdx.x;
  int l = tid & 63, w = tid >> 6;
  int g = l >> 4, q = l & 15;
  int n0 = blockIdx.x * 16;
  int n = n0 + q;
  int srow = tid >> 4, scol = (tid & 15) * 8;
  const float* wgp = Wg + ((size_t)e * INTER + n0 + srow) * HD + scol;
  const float* wup = Wu + ((size_t)e * INTER + n0 + srow) * HD + scol;
  float bgs = bg[e * INTER + n], bus = bu[e * INTER + n];
  for (int mg = blockIdx.y; mg * 256 < count; mg += 2) {
    int mbase = mg * 256 + w * 64;
    const unsigned short* ap[4];
#pragma unroll
    for (int mt = 0; mt < 4; ++mt) {
      int tok = lists[e * SEQ + min(mbase + mt * 16 + q, count - 1)];
      ap[mt] = hn + (size_t)tok * HD;
    }
    f32x4 ag[4] = {{0, 0, 0, 0}, {0, 0, 0, 0}, {0, 0, 0, 0}, {0, 0, 0, 0}};
    f32x4 au[4] = {{0, 0, 0, 0}, {0, 0, 0, 0}, {0, 0, 0, 0}, {0, 0, 0, 0}};
    float4 g0 = *(const float4*)(wgp);
    float4 g1 = *(const float4*)(wgp + 4);
    float4 u0 = *(const float4*)(wup);
    float4 u1 = *(const float4*)(wup + 4);
    for (int kc = 0; kc < HD; kc += 128) {
      __syncthreads();
      {
        float gv[8] = {g0.x, g0.y, g0.z, g0.w, g1.x, g1.y, g1.z, g1.w};
        float uv[8] = {u0.x, u0.y, u0.z, u0.w, u1.x, u1.y, u1.z, u1.w};
        short8 sg, su;
#pragma unroll
        for (int j = 0; j < 8; ++j) {
          sg[j] = (short)f2bf(gv[j]);
          su[j] = (short)f2bf(uv[j]);
        }
        *(short8*)&lwg[srow][scol] = sg;
        *(short8*)&lwu[srow][scol] = su;
      }
      __syncthreads();
      if (kc + 128 < HD) {
        g0 = *(const float4*)(wgp + kc + 128);
        g1 = *(const float4*)(wgp + kc + 128 + 4);
        u0 = *(const float4*)(wup + kc + 128);
        u1 = *(const float4*)(wup + kc + 128 + 4);
      }
#pragma unroll
      for (int kh = 0; kh < 4; ++kh) {
        short8 wgf = *(const short8*)&lwg[q][kh * 32 + 8 * g];
        short8 wuf = *(const short8*)&lwu[q][kh * 32 + 8 * g];
#pragma unroll
        for (int mt = 0; mt < 4; ++mt) {
          short8 a = *(const short8*)(ap[mt] + kc + kh * 32 + 8 * g);
          ag[mt] = mfma32(a, wgf, ag[mt]);
          au[mt] = mfma32(a, wuf, au[mt]);
        }
      }
    }
#pragma unroll
    for (int mt = 0; mt < 4; ++mt) {
#pragma unroll
      for (int r = 0; r < 4; ++r) {
        int mm = mbase + mt * 16 + 4 * g + r;
        if (mm < count) {
          float gate = ag[mt][r] + bgs, up = au[mt][r] + bus;
          float gc = fminf(gate, LIMIT);
          float uc = fminf(fmaxf(up, -LIMIT), LIMIT);
          float glu = gc / (1.f + __expf(-ALPHA * gc));
          gated[((size_t)e * SEQ + mm) * INTER + n] = f2bf((uc + 1.f) * glu);
        }
      }
    }
  }
}

// ------ MoE down grouped GEMM, LDS-staged weights, weighted atomics ---------
__global__ __launch_bounds__(256) void gemm_down(
    const unsigned short* __restrict__ gated, const float* __restrict__ Wd,
    const float* __restrict__ bd, const int* __restrict__ counts,
    const int* __restrict__ lists, const float* __restrict__ wts,
    float* __restrict__ out) {
  __shared__ __align__(16) unsigned short lwd[16][136];
  int e = blockIdx.z;
  int count = counts[e];
  int tid = threadIdx.x;
  int l = tid & 63, w = tid >> 6;
  int g = l >> 4, q = l & 15;
  int n0 = blockIdx.x * 16;
  int n = n0 + q;
  int srow = tid >> 4, scol = (tid & 15) * 8;
  const float* wdp = Wd + ((size_t)e * HD + n0 + srow) * INTER + scol;
  float bds = bd[e * HD + n];
  for (int mg = blockIdx.y; mg * 256 < count; mg += 2) {
    int mbase = mg * 256 + w * 64;
    const unsigned short* ap[4];
#pragma unroll
    for (int mt = 0; mt < 4; ++mt) {
      ap[mt] = gated + ((size_t)e * SEQ + min(mbase + mt * 16 + q, count - 1)) * INTER;
    }
    f32x4 acc[4] = {{0, 0, 0, 0}, {0, 0, 0, 0}, {0, 0, 0, 0}, {0, 0, 0, 0}};
    float4 d0 = *(const float4*)(wdp);
    float4 d1 = *(const float4*)(wdp + 4);
    for (int kc = 0; kc < INTER; kc += 128) {
      __syncthreads();
      {
        float dv[8] = {d0.x, d0.y, d0.z, d0.w, d1.x, d1.y, d1.z, d1.w};
        short8 sd;
#pragma unroll
        for (int j = 0; j < 8; ++j) sd[j] = (short)f2bf(dv[j]);
        *(short8*)&lwd[srow][scol] = sd;
      }
      __syncthreads();
      if (kc + 128 < INTER) {
        d0 = *(const float4*)(wdp + kc + 128);
        d1 = *(const float4*)(wdp + kc + 128 + 4);
      }
#pragma unroll
      for (int kh = 0; kh < 4; ++kh) {
        short8 wdf = *(const short8*)&lwd[q][kh * 32 + 8 * g];
#pragma unroll
        for (int mt = 0; mt < 4; ++mt) {
          short8 a = *(const short8*)(ap[mt] + kc + kh * 32 + 8 * g);
          acc[mt] = mfma32(a, wdf, acc[mt]);
        }
      }
    }
#pragma unroll
    for (int mt = 0; mt < 4; ++mt) {
#pragma unroll
      for (int r = 0; r < 4; ++r) {
        int mm = mbase + mt * 16 + 4 * g + r;
        if (mm < count) {
          int t = lists[e * SEQ + mm];
          float wt = wts[t * NEXP + e];
          atomicAdd(&out[(size_t)t * HD + n], (acc[mt][r] + bds) * wt);
        }
      }
    }
  }
}

extern "C" void kernel_launch(void* const* d_in, const int* in_sizes, int n_in,
                              void* d_out, int out_size, void* d_ws,
                              size_t ws_size, hipStream_t stream) {
  const float* x = (const float*)d_in[0];
  const float* ln1 = (const float*)d_in[2];
  const float* ln2 = (const float*)d_in[3];
  const float* Wq = (const float*)d_in[4];
  const float* bq = (const float*)d_in[5];
  const float* Wk = (const float*)d_in[6];
  const float* bk = (const float*)d_in[7];
  const float* Wv = (const float*)d_in[8];
  const float* bv = (const float*)d_in[9];
  const float* Wo = (const float*)d_in[10];
  const float* bo = (const float*)d_in[11];
  const float* sinks = (const float*)d_in[12];
  const float* rw = (const float*)d_in[13];
  const float* rb = (const float*)d_in[14];
  const float* Wg = (const float*)d_in[15];
  const float* bg = (const float*)d_in[16];
  const float* Wu = (const float*)d_in[17];
  const float* bu = (const float*)d_in[18];
  const float* Wd = (const float*)d_in[19];
  const float* bd = (const float*)d_in[20];
  float* out = (float*)d_out;

  char* ws = (char*)d_ws;
  size_t off = 0;
  auto alloc = [&](size_t bytes) {
    void* p = ws + off;
    off += (bytes + 255) & ~(size_t)255;
    return p;
  };
  unsigned short* xnh = (unsigned short*)alloc((size_t)SEQ * HD * 2);
  unsigned short* xnl = (unsigned short*)alloc((size_t)SEQ * HD * 2);
  unsigned short* qbh = (unsigned short*)alloc((size_t)SEQ * NHEAD * DHEAD * 2);
  unsigned short* qbl = (unsigned short*)alloc((size_t)SEQ * NHEAD * DHEAD * 2);
  unsigned short* kbh = (unsigned short*)alloc((size_t)SEQ * NKVH * DHEAD * 2);
  unsigned short* kbl = (unsigned short*)alloc((size_t)SEQ * NKVH * DHEAD * 2);
  unsigned short* vth = (unsigned short*)alloc((size_t)NKVH * DHEAD * SEQ * 2);
  unsigned short* vtl = (unsigned short*)alloc((size_t)NKVH * DHEAD * SEQ * 2);
  unsigned short* ath = (unsigned short*)alloc((size_t)SEQ * NHEAD * DHEAD * 2);
  unsigned short* atl = (unsigned short*)alloc((size_t)SEQ * NHEAD * DHEAD * 2);
  float* hbuf = (float*)alloc((size_t)SEQ * HD * 4);
  unsigned short* hn = (unsigned short*)alloc((size_t)SEQ * HD * 2);
  float* wts = (float*)alloc((size_t)SEQ * NEXP * 4);
  int* counts = (int*)alloc(NEXP * 4);
  int* lists = (int*)alloc((size_t)NEXP * SEQ * 4);
  unsigned short* gated = (unsigned short*)alloc((size_t)NEXP * SEQ * INTER * 2);
  (void)ws_size;
  (void)off;

  rmsnorm_split_kernel<<<SEQ, 256, 0, stream>>>(x, ln1, xnh, xnl);
  gemm_split<0><<<dim3(NHEAD * DHEAD / 16, SEQ / 256), 256, 0, stream>>>(
      xnh, xnl, Wq, bq, nullptr, qbh, qbl, nullptr, nullptr, SEQ, NHEAD * DHEAD, HD);
  gemm_split<0><<<dim3(NKVH * DHEAD / 16, SEQ / 256), 256, 0, stream>>>(
      xnh, xnl, Wk, bk, nullptr, kbh, kbl, nullptr, nullptr, SEQ, NKVH * DHEAD, HD);
  gemm_split<1><<<dim3(NKVH * DHEAD / 16, SEQ / 256), 256, 0, stream>>>(
      xnh, xnl, Wv, bv, nullptr, vth, vtl, nullptr, nullptr, SEQ, NKVH * DHEAD, HD);
  attn_kernel<<<NHEAD * 64 / 4, 256, 0, stream>>>(qbh, qbl, kbh, kbl, vth, vtl,
                                                  sinks, ath, atl);
  gemm_split<2><<<dim3(HD / 16, SEQ / 256), 256, 0, stream>>>(
      ath, atl, Wo, bo, x, nullptr, nullptr, hbuf, out, SEQ, HD, NHEAD * DHEAD);
  rmsnorm_plain_kernel<<<SEQ, 256, 0, stream>>>(hbuf, ln2, hn);
  hipMemsetAsync(counts, 0, NEXP * sizeof(int), stream);
  router_kernel<<<SEQ, 64, 0, stream>>>(hbuf, ln2, rw, rb, wts, counts, lists);
  gemm_gateup<<<dim3(INTER / 16, 2, NEXP), 256, 0, stream>>>(
      hn, Wg, bg, Wu, bu, counts, lists, gated);
  gemm_down<<<dim3(HD / 16, 2, NEXP), 256, 0, stream>>>(
      gated, Wd, bd, counts, lists, wts, out);
}

// Round 5
// 667.878 us; speedup vs baseline: 2.6607x; 1.4084x over previous
//
#include <hip/hip_runtime.h>
#include <hip/hip_bf16.h>

#define HD 2048
#define SEQ 1024
#define NHEAD 32
#define NKVH 8
#define DHEAD 64
#define NEXP 8
#define INTER 2048
#define SCALE 0.125f
#define ALPHA 1.702f
#define LIMIT 7.0f

typedef __attribute__((ext_vector_type(8))) short short8;
typedef __attribute__((ext_vector_type(4))) short short4v;
typedef __attribute__((ext_vector_type(4))) float f32x4;

__device__ __forceinline__ unsigned short f2bf(float f) {
  union { float f; unsigned u; } v; v.f = f;
  unsigned r = v.u + 0x7fffu + ((v.u >> 16) & 1u);
  return (unsigned short)(r >> 16);
}
__device__ __forceinline__ float bf2f(unsigned short h) {
  union { unsigned u; float f; } v; v.u = ((unsigned)h) << 16; return v.f;
}
__device__ __forceinline__ void split2(float f, unsigned short& hi, unsigned short& lo) {
  hi = f2bf(f);
  lo = f2bf(f - bf2f(hi));
}

__device__ __forceinline__ f32x4 mfma32(short8 a, short8 b, f32x4 c) {
  return __builtin_amdgcn_mfma_f32_16x16x32_bf16(a, b, c, 0, 0, 0);
}

// ---------------- RMSNorm fp32 -> split bf16 (hi/lo) ----------------
__global__ __launch_bounds__(256) void rmsnorm_split_kernel(
    const float* __restrict__ x, const float* __restrict__ gamma,
    unsigned short* __restrict__ oh, unsigned short* __restrict__ ol) {
  int row = blockIdx.x, tid = threadIdx.x;
  const float* xr = x + (size_t)row * HD;
  float v[8];
#pragma unroll
  for (int i = 0; i < 8; ++i) v[i] = xr[tid * 8 + i];
  float ss = 0.f;
#pragma unroll
  for (int i = 0; i < 8; ++i) ss += v[i] * v[i];
#pragma unroll
  for (int off = 32; off; off >>= 1) ss += __shfl_xor(ss, off, 64);
  __shared__ float wss[4];
  if ((tid & 63) == 0) wss[tid >> 6] = ss;
  __syncthreads();
  float rs = rsqrtf((wss[0] + wss[1] + wss[2] + wss[3]) * (1.0f / HD) + 1e-5f);
  short8 vh, vl;
#pragma unroll
  for (int i = 0; i < 8; ++i) {
    float val = v[i] * rs * gamma[tid * 8 + i];
    unsigned short h, lo;
    split2(val, h, lo);
    vh[i] = (short)h;
    vl[i] = (short)lo;
  }
  *(short8*)(oh + (size_t)row * HD + tid * 8) = vh;
  *(short8*)(ol + (size_t)row * HD + tid * 8) = vl;
}

// ---------------- RMSNorm fp32 -> single bf16 (MoE input) ----------------
__global__ __launch_bounds__(256) void rmsnorm_plain_kernel(
    const float* __restrict__ x, const float* __restrict__ gamma,
    unsigned short* __restrict__ out) {
  int row = blockIdx.x, tid = threadIdx.x;
  const float* xr = x + (size_t)row * HD;
  float v[8];
#pragma unroll
  for (int i = 0; i < 8; ++i) v[i] = xr[tid * 8 + i];
  float ss = 0.f;
#pragma unroll
  for (int i = 0; i < 8; ++i) ss += v[i] * v[i];
#pragma unroll
  for (int off = 32; off; off >>= 1) ss += __shfl_xor(ss, off, 64);
  __shared__ float wss[4];
  if ((tid & 63) == 0) wss[tid >> 6] = ss;
  __syncthreads();
  float rs = rsqrtf((wss[0] + wss[1] + wss[2] + wss[3]) * (1.0f / HD) + 1e-5f);
  short8 o;
#pragma unroll
  for (int i = 0; i < 8; ++i) o[i] = (short)f2bf(v[i] * rs * gamma[tid * 8 + i]);
  *(short8*)(out + (size_t)row * HD + tid * 8) = o;
}

// ---------------- Unified weight-streaming GEMM ------------------------------
// Block: 4 waves, n-tile = NS*16 cols, m-group = MT*64 rows (wave = MT m-subtiles).
// Weights (fp32, row-major [N][K]) cooperatively staged: reg-prefetch one
// 128-chunk ahead, converted to bf16 (split hi/lo if SPLIT) once, LDS tile
// [NR][136] (272B rows -> ~2-way bank aliasing). A (bf16) reg-prefetched one
// 32-k step ahead. acc = Ah*Wh (+ Ah*Wl + Al*Wh if SPLIT).
// EPI 0: fused QKV (regions Q[0,2048) K[2048,2560) V[2560,3072)), split outs,
//        V transposed. EPI 1: O-proj, f32 out = acc+bias+resid.
// EPI 2: MoE gate/up (z = e*2+mat), raw f32 out [slot][INTER].
// EPI 3: MoE down, raw f32 out [slot][HD].
template <int MT, int NS, bool SPLIT, int EPI>
__global__ __launch_bounds__(256) void gemm_ws(
    const unsigned short* __restrict__ Ah, const unsigned short* __restrict__ Al,
    int ldA,
    const float* __restrict__ W0, const float* __restrict__ W1,
    const float* __restrict__ W2,
    const float* __restrict__ b0, const float* __restrict__ b1,
    const float* __restrict__ b2,
    const float* __restrict__ resid,
    const int* __restrict__ counts, const int* __restrict__ arows,
    const int* __restrict__ orows,
    unsigned short* __restrict__ oh0, unsigned short* __restrict__ ol0,
    unsigned short* __restrict__ oh1, unsigned short* __restrict__ ol1,
    unsigned short* __restrict__ oh2, unsigned short* __restrict__ ol2,
    float* __restrict__ f0, float* __restrict__ f1,
    int M, int Kd) {
  constexpr int MG = MT * 64;
  constexpr int NR = NS * 16;
  constexpr int TPR = 256 / NR;   // threads per W row
  constexpr int CPT = 128 / TPR;  // fp32 cols per thread per chunk
  constexpr int NF4 = CPT / 4;    // float4 loads per thread per matrix chunk
  __shared__ __align__(16) unsigned short lw[2][NR][136];
  int tid = threadIdx.x;
  int l = tid & 63, w = tid >> 6;
  int g = l >> 4, q = l & 15;
  int n0 = blockIdx.x * NR;

  const float* Wb;
  const float* bias;
  int nloc = n0, e = 0, mat = 0;
  if constexpr (EPI == 0) {
    if (n0 < NHEAD * DHEAD) {
      Wb = W0; bias = b0;
    } else if (n0 < NHEAD * DHEAD + NKVH * DHEAD) {
      Wb = W1; bias = b1; nloc = n0 - NHEAD * DHEAD;
    } else {
      Wb = W2; bias = b2; nloc = n0 - (NHEAD * DHEAD + NKVH * DHEAD);
    }
  } else if constexpr (EPI == 1) {
    Wb = W0; bias = b0;
  } else if constexpr (EPI == 2) {
    e = blockIdx.z >> 1;
    mat = blockIdx.z & 1;
    Wb = (mat ? W1 : W0) + (size_t)e * INTER * HD;
    bias = (mat ? b1 : b0) + (size_t)e * INTER;
  } else {
    e = blockIdx.z;
    Wb = W0 + (size_t)e * HD * INTER;
    bias = b0 + (size_t)e * HD;
  }
  int cnt = (EPI >= 2) ? counts[e] : M;
  const float* wrow = Wb + (size_t)(nloc + tid / TPR) * Kd + (tid % TPR) * CPT;
  int wcc = (tid % TPR) * CPT;
  int wrr = tid / TPR;

  for (int mg = blockIdx.y; mg * MG < cnt; mg += gridDim.y) {
    int mb = mg * MG + w * (MT * 16);
    const unsigned short* ap[MT];
    const unsigned short* apl[MT];
#pragma unroll
    for (int mt = 0; mt < MT; ++mt) {
      int mm = min(mb + mt * 16 + q, cnt - 1);
      int ar = (EPI >= 2) ? arows[e * SEQ + mm] : mm;
      ap[mt] = Ah + (size_t)ar * ldA + 8 * g;
      if constexpr (SPLIT) apl[mt] = Al + (size_t)ar * ldA + 8 * g;
    }
    f32x4 acc[MT][NS];
#pragma unroll
    for (int mt = 0; mt < MT; ++mt)
#pragma unroll
      for (int ns = 0; ns < NS; ++ns) acc[mt][ns] = (f32x4){0.f, 0.f, 0.f, 0.f};
    float4 wpre[NF4];
#pragma unroll
    for (int j = 0; j < NF4; ++j) wpre[j] = *(const float4*)(wrow + 4 * j);
    short8 apre[MT], aprl[MT];
#pragma unroll
    for (int mt = 0; mt < MT; ++mt) {
      apre[mt] = *(const short8*)(ap[mt]);
      if constexpr (SPLIT) aprl[mt] = *(const short8*)(apl[mt]);
    }
    for (int kc = 0; kc < Kd; kc += 128) {
      __syncthreads();
#pragma unroll
      for (int j = 0; j < NF4; j += 2) {
        float v[8] = {wpre[j].x,     wpre[j].y,     wpre[j].z,     wpre[j].w,
                      wpre[j + 1].x, wpre[j + 1].y, wpre[j + 1].z, wpre[j + 1].w};
        short8 hh, ll;
#pragma unroll
        for (int jj = 0; jj < 8; ++jj) {
          if constexpr (SPLIT) {
            unsigned short h, lo;
            split2(v[jj], h, lo);
            hh[jj] = (short)h;
            ll[jj] = (short)lo;
          } else {
            hh[jj] = (short)f2bf(v[jj]);
          }
        }
        *(short8*)&lw[0][wrr][wcc + j * 4] = hh;
        if constexpr (SPLIT) *(short8*)&lw[1][wrr][wcc + j * 4] = ll;
      }
      __syncthreads();
      if (kc + 128 < Kd) {
#pragma unroll
        for (int j = 0; j < NF4; ++j)
          wpre[j] = *(const float4*)(wrow + kc + 128 + 4 * j);
      }
#pragma unroll
      for (int kh = 0; kh < 4; ++kh) {
        short8 acur[MT], acl[MT];
#pragma unroll
        for (int mt = 0; mt < MT; ++mt) {
          acur[mt] = apre[mt];
          if constexpr (SPLIT) acl[mt] = aprl[mt];
        }
        int kn = kc + kh * 32 + 32;
        if (kn < Kd) {
#pragma unroll
          for (int mt = 0; mt < MT; ++mt) {
            apre[mt] = *(const short8*)(ap[mt] + kn);
            if constexpr (SPLIT) aprl[mt] = *(const short8*)(apl[mt] + kn);
          }
        }
        short8 wh[NS], wl[NS];
#pragma unroll
        for (int ns = 0; ns < NS; ++ns) {
          wh[ns] = *(const short8*)&lw[0][ns * 16 + q][kh * 32 + 8 * g];
          if constexpr (SPLIT)
            wl[ns] = *(const short8*)&lw[1][ns * 16 + q][kh * 32 + 8 * g];
        }
#pragma unroll
        for (int mt = 0; mt < MT; ++mt)
#pragma unroll
          for (int ns = 0; ns < NS; ++ns) {
            acc[mt][ns] = mfma32(acur[mt], wh[ns], acc[mt][ns]);
            if constexpr (SPLIT) {
              acc[mt][ns] = mfma32(acur[mt], wl[ns], acc[mt][ns]);
              acc[mt][ns] = mfma32(acl[mt], wh[ns], acc[mt][ns]);
            }
          }
      }
    }
    // ---------------- epilogue ----------------
#pragma unroll
    for (int ns = 0; ns < NS; ++ns) {
      int ncol = nloc + ns * 16 + q;
      float bs = bias[ncol];
#pragma unroll
      for (int mt = 0; mt < MT; ++mt) {
#pragma unroll
        for (int r = 0; r < 4; ++r) {
          int mr = mb + mt * 16 + 4 * g + r;
          float val = acc[mt][ns][r] + bs;
          if constexpr (EPI == 0) {
            unsigned short h, lo;
            split2(val, h, lo);
            if (n0 < NHEAD * DHEAD) {
              oh0[(size_t)mr * (NHEAD * DHEAD) + ncol] = h;
              ol0[(size_t)mr * (NHEAD * DHEAD) + ncol] = lo;
            } else if (n0 < NHEAD * DHEAD + NKVH * DHEAD) {
              oh1[(size_t)mr * (NKVH * DHEAD) + ncol] = h;
              ol1[(size_t)mr * (NKVH * DHEAD) + ncol] = lo;
            } else {
              oh2[(size_t)ncol * SEQ + mr] = h;
              ol2[(size_t)ncol * SEQ + mr] = lo;
            }
          } else if constexpr (EPI == 1) {
            f0[(size_t)mr * HD + ncol] = val + resid[(size_t)mr * HD + ncol];
          } else if constexpr (EPI == 2) {
            if (mr < cnt) {
              int slot = orows[e * SEQ + mr];
              (mat ? f1 : f0)[(size_t)slot * INTER + ncol] = val;
            }
          } else {
            if (mr < cnt) {
              int slot = orows[e * SEQ + mr];
              f0[(size_t)slot * HD + ncol] = val;
            }
          }
        }
      }
    }
  }
}

// ---------------- Flash attention with sink, split precision ----------------
__global__ __launch_bounds__(256) void attn_kernel(
    const unsigned short* __restrict__ Qh, const unsigned short* __restrict__ Ql,
    const unsigned short* __restrict__ Kh, const unsigned short* __restrict__ Kl,
    const unsigned short* __restrict__ Vh, const unsigned short* __restrict__ Vl,
    const float* __restrict__ sinks, unsigned short* __restrict__ outh,
    unsigned short* __restrict__ outl) {
  __shared__ __align__(16) unsigned short pbuf[4][2][16][40];
  int l = threadIdx.x & 63, widx = threadIdx.x >> 6;
  int wid = blockIdx.x * 4 + widx;
  int head = wid >> 6, qt = wid & 63;
  int q0 = qt * 16;
  int g = l >> 4, q = l & 15;
  int kvh = head >> 2;
  size_t qoff = (size_t)(q0 + q) * (NHEAD * DHEAD) + head * DHEAD + 8 * g;
  short8 qh0 = *(const short8*)(Qh + qoff);
  short8 qh1 = *(const short8*)(Qh + qoff + 32);
  short8 ql0 = *(const short8*)(Ql + qoff);
  short8 ql1 = *(const short8*)(Ql + qoff + 32);
  float m = sinks[head];
  float lsum = 1.0f;
  f32x4 o[4] = {{0, 0, 0, 0}, {0, 0, 0, 0}, {0, 0, 0, 0}, {0, 0, 0, 0}};
  int qglob = q0 + q;
  for (int kt = 0; kt <= qt; kt += 2) {
    bool hasB = (kt + 1) <= qt;
    size_t koff = (size_t)(kt * 16 + q) * (NKVH * DHEAD) + kvh * DHEAD + 8 * g;
    f32x4 stA = {0, 0, 0, 0};
    {
      short8 kh0 = *(const short8*)(Kh + koff);
      short8 kh1 = *(const short8*)(Kh + koff + 32);
      short8 kl0 = *(const short8*)(Kl + koff);
      short8 kl1 = *(const short8*)(Kl + koff + 32);
      stA = mfma32(kh0, qh0, stA);
      stA = mfma32(kh0, ql0, stA);
      stA = mfma32(kl0, qh0, stA);
      stA = mfma32(kh1, qh1, stA);
      stA = mfma32(kh1, ql1, stA);
      stA = mfma32(kl1, qh1, stA);
    }
    f32x4 stB = {0, 0, 0, 0};
    if (hasB) {
      size_t koff2 = koff + (size_t)16 * (NKVH * DHEAD);
      short8 kh0 = *(const short8*)(Kh + koff2);
      short8 kh1 = *(const short8*)(Kh + koff2 + 32);
      short8 kl0 = *(const short8*)(Kl + koff2);
      short8 kl1 = *(const short8*)(Kl + koff2 + 32);
      stB = mfma32(kh0, qh0, stB);
      stB = mfma32(kh0, ql0, stB);
      stB = mfma32(kl0, qh0, stB);
      stB = mfma32(kh1, qh1, stB);
      stB = mfma32(kh1, ql1, stB);
      stB = mfma32(kl1, qh1, stB);
    }
    float sA[4], sB[4];
#pragma unroll
    for (int r = 0; r < 4; ++r) {
      int keyA = kt * 16 + 4 * g + r;
      sA[r] = (keyA <= qglob) ? stA[r] * SCALE : -1e30f;
      sB[r] = (hasB && keyA + 16 <= qglob) ? stB[r] * SCALE : -1e30f;
    }
    float mt = fmaxf(fmaxf(fmaxf(sA[0], sA[1]), fmaxf(sA[2], sA[3])),
                     fmaxf(fmaxf(sB[0], sB[1]), fmaxf(sB[2], sB[3])));
    mt = fmaxf(mt, __shfl_xor(mt, 16, 64));
    mt = fmaxf(mt, __shfl_xor(mt, 32, 64));
    float mnew = fmaxf(m, mt);
    float corr = __expf(m - mnew);
    float pA[4], pB[4];
    float rsum = 0.f;
#pragma unroll
    for (int r = 0; r < 4; ++r) {
      pA[r] = __expf(sA[r] - mnew);
      pB[r] = __expf(sB[r] - mnew);
      rsum += pA[r] + pB[r];
    }
    rsum += __shfl_xor(rsum, 16, 64);
    rsum += __shfl_xor(rsum, 32, 64);
    lsum = lsum * corr + rsum;
    m = mnew;
#pragma unroll
    for (int dt = 0; dt < 4; ++dt)
#pragma unroll
      for (int r = 0; r < 4; ++r) o[dt][r] *= corr;
    unsigned short ph[8], pl[8];
#pragma unroll
    for (int r = 0; r < 4; ++r) {
      split2(pA[r], ph[r], pl[r]);
      split2(pB[r], ph[4 + r], pl[4 + r]);
    }
    short4v wAh = {(short)ph[0], (short)ph[1], (short)ph[2], (short)ph[3]};
    short4v wBh = {(short)ph[4], (short)ph[5], (short)ph[6], (short)ph[7]};
    short4v wAl = {(short)pl[0], (short)pl[1], (short)pl[2], (short)pl[3]};
    short4v wBl = {(short)pl[4], (short)pl[5], (short)pl[6], (short)pl[7]};
    *(short4v*)&pbuf[widx][0][q][4 * g] = wAh;
    *(short4v*)&pbuf[widx][0][q][16 + 4 * g] = wBh;
    *(short4v*)&pbuf[widx][1][q][4 * g] = wAl;
    *(short4v*)&pbuf[widx][1][q][16 + 4 * g] = wBl;
    asm volatile("s_waitcnt lgkmcnt(0)" ::: "memory");
    short8 pbh = *(const short8*)&pbuf[widx][0][q][8 * g];
    short8 pbl = *(const short8*)&pbuf[widx][1][q][8 * g];
    size_t vbase = (size_t)(kvh * DHEAD) * SEQ + kt * 16 + 8 * g;
#pragma unroll
    for (int dt = 0; dt < 4; ++dt) {
      size_t voff = vbase + (size_t)(dt * 16 + q) * SEQ;
      short8 vh8 = *(const short8*)(Vh + voff);
      short8 vl8 = *(const short8*)(Vl + voff);
      o[dt] = mfma32(vh8, pbh, o[dt]);
      o[dt] = mfma32(vh8, pbl, o[dt]);
      o[dt] = mfma32(vl8, pbh, o[dt]);
    }
  }
  float inv = 1.0f / lsum;
#pragma unroll
  for (int dt = 0; dt < 4; ++dt)
#pragma unroll
    for (int r = 0; r < 4; ++r) {
      float val = o[dt][r] * inv;
      unsigned short h, lo;
      split2(val, h, lo);
      size_t idx = (size_t)qglob * (NHEAD * DHEAD) + head * DHEAD + dt * 16 + 4 * g + r;
      outh[idx] = h;
      outl[idx] = lo;
    }
}

// ---------------- Router: fp64 norm + logits, top-2, slot/weight lists -------
__global__ __launch_bounds__(64) void router_kernel(
    const float* __restrict__ h, const float* __restrict__ gamma,
    const float* __restrict__ rw, const float* __restrict__ rb,
    float* __restrict__ wsel, int* __restrict__ counts,
    int* __restrict__ lists, int* __restrict__ slotof) {
  int t = blockIdx.x;
  int l = threadIdx.x;
  const float* hr = h + (size_t)t * HD;
  double ss = 0.0;
  for (int i = l; i < HD; i += 64) {
    double x = (double)hr[i];
    ss += x * x;
  }
#pragma unroll
  for (int off = 32; off; off >>= 1) ss += __shfl_xor(ss, off, 64);
  double rs = rsqrt(ss * (1.0 / HD) + 1e-5);
  double acc[NEXP];
#pragma unroll
  for (int e = 0; e < NEXP; ++e) acc[e] = 0.0;
  for (int i = l; i < HD; i += 64) {
    double xh = (double)hr[i] * rs * (double)gamma[i];
#pragma unroll
    for (int e = 0; e < NEXP; ++e) acc[e] += xh * (double)rw[e * HD + i];
  }
#pragma unroll
  for (int e = 0; e < NEXP; ++e)
#pragma unroll
    for (int off = 32; off; off >>= 1) acc[e] += __shfl_xor(acc[e], off, 64);
  if (l == 0) {
    double lg[NEXP];
#pragma unroll
    for (int e = 0; e < NEXP; ++e) lg[e] = acc[e] + (double)rb[e];
    int e0 = 0;
#pragma unroll
    for (int e = 1; e < NEXP; ++e)
      if (lg[e] > lg[e0]) e0 = e;
    int e1 = -1;
#pragma unroll
    for (int e = 0; e < NEXP; ++e)
      if (e != e0 && (e1 < 0 || lg[e] > lg[e1])) e1 = e;
    double d = exp(lg[e1] - lg[e0]);
    float p0 = (float)(1.0 / (1.0 + d)), p1 = (float)(d / (1.0 + d));
    wsel[2 * t] = p0;
    wsel[2 * t + 1] = p1;
    int s0 = atomicAdd(&counts[e0], 1);
    lists[e0 * SEQ + s0] = t;
    slotof[e0 * SEQ + s0] = 2 * t;
    int s1 = atomicAdd(&counts[e1], 1);
    lists[e1 * SEQ + s1] = t;
    slotof[e1 * SEQ + s1] = 2 * t + 1;
  }
}

// ---------------- MoE activation: raw gate/up -> gated bf16 -----------------
__global__ __launch_bounds__(256) void act_kernel(
    const float* __restrict__ rg, const float* __restrict__ ru,
    unsigned short* __restrict__ gated) {
  size_t base = (size_t)blockIdx.x * INTER + threadIdx.x * 8;
  float4 g0 = *(const float4*)(rg + base);
  float4 g1 = *(const float4*)(rg + base + 4);
  float4 u0 = *(const float4*)(ru + base);
  float4 u1 = *(const float4*)(ru + base + 4);
  float gv[8] = {g0.x, g0.y, g0.z, g0.w, g1.x, g1.y, g1.z, g1.w};
  float uv[8] = {u0.x, u0.y, u0.z, u0.w, u1.x, u1.y, u1.z, u1.w};
  short8 o;
#pragma unroll
  for (int j = 0; j < 8; ++j) {
    float gc = fminf(gv[j], LIMIT);
    float uc = fminf(fmaxf(uv[j], -LIMIT), LIMIT);
    float glu = gc / (1.f + __expf(-ALPHA * gc));
    o[j] = (short)f2bf((uc + 1.f) * glu);
  }
  *(short8*)(gated + base) = o;
}

// ---------------- Final: out = h + w0*down[2t] + w1*down[2t+1] --------------
__global__ __launch_bounds__(256) void reduce_kernel(
    const float* __restrict__ hbuf, const float* __restrict__ scr,
    const float* __restrict__ wsel, float* __restrict__ out) {
  int t = blockIdx.x;
  int c = threadIdx.x * 8;
  float w0 = wsel[2 * t], w1 = wsel[2 * t + 1];
  size_t hb = (size_t)t * HD + c;
  size_t s0 = (size_t)(2 * t) * HD + c;
  size_t s1 = (size_t)(2 * t + 1) * HD + c;
#pragma unroll
  for (int j = 0; j < 2; ++j) {
    float4 hv = *(const float4*)(hbuf + hb + 4 * j);
    float4 a = *(const float4*)(scr + s0 + 4 * j);
    float4 b = *(const float4*)(scr + s1 + 4 * j);
    float4 r;
    r.x = hv.x + w0 * a.x + w1 * b.x;
    r.y = hv.y + w0 * a.y + w1 * b.y;
    r.z = hv.z + w0 * a.z + w1 * b.z;
    r.w = hv.w + w0 * a.w + w1 * b.w;
    *(float4*)(out + hb + 4 * j) = r;
  }
}

extern "C" void kernel_launch(void* const* d_in, const int* in_sizes, int n_in,
                              void* d_out, int out_size, void* d_ws,
                              size_t ws_size, hipStream_t stream) {
  const float* x = (const float*)d_in[0];
  const float* ln1 = (const float*)d_in[2];
  const float* ln2 = (const float*)d_in[3];
  const float* Wq = (const float*)d_in[4];
  const float* bq = (const float*)d_in[5];
  const float* Wk = (const float*)d_in[6];
  const float* bk = (const float*)d_in[7];
  const float* Wv = (const float*)d_in[8];
  const float* bv = (const float*)d_in[9];
  const float* Wo = (const float*)d_in[10];
  const float* bo = (const float*)d_in[11];
  const float* sinks = (const float*)d_in[12];
  const float* rw = (const float*)d_in[13];
  const float* rb = (const float*)d_in[14];
  const float* Wg = (const float*)d_in[15];
  const float* bg = (const float*)d_in[16];
  const float* Wu = (const float*)d_in[17];
  const float* bu = (const float*)d_in[18];
  const float* Wd = (const float*)d_in[19];
  const float* bd = (const float*)d_in[20];
  float* out = (float*)d_out;

  char* ws = (char*)d_ws;
  size_t off = 0;
  auto alloc = [&](size_t bytes) {
    void* p = ws + off;
    off += (bytes + 255) & ~(size_t)255;
    return p;
  };
  unsigned short* xnh = (unsigned short*)alloc((size_t)SEQ * HD * 2);
  unsigned short* xnl = (unsigned short*)alloc((size_t)SEQ * HD * 2);
  unsigned short* qbh = (unsigned short*)alloc((size_t)SEQ * NHEAD * DHEAD * 2);
  unsigned short* qbl = (unsigned short*)alloc((size_t)SEQ * NHEAD * DHEAD * 2);
  unsigned short* kbh = (unsigned short*)alloc((size_t)SEQ * NKVH * DHEAD * 2);
  unsigned short* kbl = (unsigned short*)alloc((size_t)SEQ * NKVH * DHEAD * 2);
  unsigned short* vth = (unsigned short*)alloc((size_t)NKVH * DHEAD * SEQ * 2);
  unsigned short* vtl = (unsigned short*)alloc((size_t)NKVH * DHEAD * SEQ * 2);
  unsigned short* ath = (unsigned short*)alloc((size_t)SEQ * NHEAD * DHEAD * 2);
  unsigned short* atl = (unsigned short*)alloc((size_t)SEQ * NHEAD * DHEAD * 2);
  float* hbuf = (float*)alloc((size_t)SEQ * HD * 4);
  unsigned short* hn = (unsigned short*)alloc((size_t)SEQ * HD * 2);
  float* wsel = (float*)alloc((size_t)SEQ * 2 * 4);
  int* counts = (int*)alloc(NEXP * 4);
  int* lists = (int*)alloc((size_t)NEXP * SEQ * 4);
  int* slotof = (int*)alloc((size_t)NEXP * SEQ * 4);
  float* rawg = (float*)alloc((size_t)2 * SEQ * INTER * 4);
  float* rawu = (float*)alloc((size_t)2 * SEQ * INTER * 4);
  unsigned short* gated = (unsigned short*)alloc((size_t)2 * SEQ * INTER * 2);
  float* scr = rawg;  // down-proj scratch aliases rawg (stream-ordered safe)
  (void)ws_size;
  (void)off;

  rmsnorm_split_kernel<<<SEQ, 256, 0, stream>>>(x, ln1, xnh, xnl);
  // fused QKV projection: N = 2048 + 512 + 512 = 3072 cols
  gemm_ws<4, 2, true, 0><<<dim3(96, 4, 1), 256, 0, stream>>>(
      xnh, xnl, HD, Wq, Wk, Wv, bq, bk, bv, nullptr, nullptr, nullptr, nullptr,
      qbh, qbl, kbh, kbl, vth, vtl, nullptr, nullptr, SEQ, HD);
  attn_kernel<<<NHEAD * 64 / 4, 256, 0, stream>>>(qbh, qbl, kbh, kbl, vth, vtl,
                                                  sinks, ath, atl);
  gemm_ws<4, 2, true, 1><<<dim3(64, 4, 1), 256, 0, stream>>>(
      ath, atl, NHEAD * DHEAD, Wo, nullptr, nullptr, bo, nullptr, nullptr, x,
      nullptr, nullptr, nullptr, nullptr, nullptr, nullptr, nullptr, nullptr,
      nullptr, hbuf, nullptr, SEQ, NHEAD * DHEAD);
  rmsnorm_plain_kernel<<<SEQ, 256, 0, stream>>>(hbuf, ln2, hn);
  hipMemsetAsync(counts, 0, NEXP * sizeof(int), stream);
  router_kernel<<<SEQ, 64, 0, stream>>>(hbuf, ln2, rw, rb, wsel, counts, lists,
                                        slotof);
  // gate+up fused over z (e*2 + mat): 64 n-blocks x 16 z = 1024 blocks
  gemm_ws<5, 2, false, 2><<<dim3(64, 1, 16), 256, 0, stream>>>(
      hn, nullptr, HD, Wg, Wu, nullptr, bg, bu, nullptr, nullptr, counts, lists,
      slotof, nullptr, nullptr, nullptr, nullptr, nullptr, nullptr, rawg, rawu,
      SEQ, HD);
  act_kernel<<<2 * SEQ, 256, 0, stream>>>(rawg, rawu, gated);
  gemm_ws<5, 2, false, 3><<<dim3(64, 1, 8), 256, 0, stream>>>(
      gated, nullptr, INTER, Wd, nullptr, nullptr, bd, nullptr, nullptr,
      nullptr, counts, slotof, slotof, nullptr, nullptr, nullptr, nullptr,
      nullptr, nullptr, scr, nullptr, SEQ, INTER);
  reduce_kernel<<<SEQ, 256, 0, stream>>>(hbuf, scr, wsel, out);
}

// Round 6
// 663.573 us; speedup vs baseline: 2.6780x; 1.0065x over previous
//
#include <hip/hip_runtime.h>
#include <hip/hip_bf16.h>

#define HD 2048
#define SEQ 1024
#define NHEAD 32
#define NKVH 8
#define DHEAD 64
#define NEXP 8
#define INTER 2048
#define SCALE 0.125f
#define ALPHA 1.702f
#define LIMIT 7.0f

typedef __attribute__((ext_vector_type(8))) short short8;
typedef __attribute__((ext_vector_type(4))) short short4v;
typedef __attribute__((ext_vector_type(4))) float f32x4;

__device__ __forceinline__ unsigned short f2bf(float f) {
  union { float f; unsigned u; } v; v.f = f;
  unsigned r = v.u + 0x7fffu + ((v.u >> 16) & 1u);
  return (unsigned short)(r >> 16);
}
__device__ __forceinline__ float bf2f(unsigned short h) {
  union { unsigned u; float f; } v; v.u = ((unsigned)h) << 16; return v.f;
}
__device__ __forceinline__ void split2(float f, unsigned short& hi, unsigned short& lo) {
  hi = f2bf(f);
  lo = f2bf(f - bf2f(hi));
}

__device__ __forceinline__ f32x4 mfma32(short8 a, short8 b, f32x4 c) {
  return __builtin_amdgcn_mfma_f32_16x16x32_bf16(a, b, c, 0, 0, 0);
}

// ---------------- RMSNorm fp32 -> split bf16 (hi/lo) ----------------
__global__ __launch_bounds__(256) void rmsnorm_split_kernel(
    const float* __restrict__ x, const float* __restrict__ gamma,
    unsigned short* __restrict__ oh, unsigned short* __restrict__ ol) {
  int row = blockIdx.x, tid = threadIdx.x;
  const float* xr = x + (size_t)row * HD;
  float v[8];
#pragma unroll
  for (int i = 0; i < 8; ++i) v[i] = xr[tid * 8 + i];
  float ss = 0.f;
#pragma unroll
  for (int i = 0; i < 8; ++i) ss += v[i] * v[i];
#pragma unroll
  for (int off = 32; off; off >>= 1) ss += __shfl_xor(ss, off, 64);
  __shared__ float wss[4];
  if ((tid & 63) == 0) wss[tid >> 6] = ss;
  __syncthreads();
  float rs = rsqrtf((wss[0] + wss[1] + wss[2] + wss[3]) * (1.0f / HD) + 1e-5f);
  short8 vh, vl;
#pragma unroll
  for (int i = 0; i < 8; ++i) {
    float val = v[i] * rs * gamma[tid * 8 + i];
    unsigned short h, lo;
    split2(val, h, lo);
    vh[i] = (short)h;
    vl[i] = (short)lo;
  }
  *(short8*)(oh + (size_t)row * HD + tid * 8) = vh;
  *(short8*)(ol + (size_t)row * HD + tid * 8) = vl;
}

// ---------------- RMSNorm fp32 -> single bf16 (MoE input) ----------------
__global__ __launch_bounds__(256) void rmsnorm_plain_kernel(
    const float* __restrict__ x, const float* __restrict__ gamma,
    unsigned short* __restrict__ out) {
  int row = blockIdx.x, tid = threadIdx.x;
  const float* xr = x + (size_t)row * HD;
  float v[8];
#pragma unroll
  for (int i = 0; i < 8; ++i) v[i] = xr[tid * 8 + i];
  float ss = 0.f;
#pragma unroll
  for (int i = 0; i < 8; ++i) ss += v[i] * v[i];
#pragma unroll
  for (int off = 32; off; off >>= 1) ss += __shfl_xor(ss, off, 64);
  __shared__ float wss[4];
  if ((tid & 63) == 0) wss[tid >> 6] = ss;
  __syncthreads();
  float rs = rsqrtf((wss[0] + wss[1] + wss[2] + wss[3]) * (1.0f / HD) + 1e-5f);
  short8 o;
#pragma unroll
  for (int i = 0; i < 8; ++i) o[i] = (short)f2bf(v[i] * rs * gamma[tid * 8 + i]);
  *(short8*)(out + (size_t)row * HD + tid * 8) = o;
}

// ---------------- Unified weight-streaming GEMM, pipelined -------------------
// Block: 4 waves, n-tile = NS*16, m-group = MT*64 (wave owns MT m-subtiles).
// Schedule per 128-k chunk (ONE barrier per chunk):
//   - at chunk start: issue fp32 W loads for chunk+1 (HBM latency hidden
//     under this chunk's MFMAs)
//   - kh=0..3: consume A regs ab[kh&1] (issued 2 kh-steps earlier -> L2
//     latency hidden), ds_read W frags from lw[cb], MFMA; prefetch A kh+2
//   - end: convert W(chunk+1) once, ds_write to lw[cb^1]; __syncthreads()
// EPI 0: fused QKV (Q[0,2048) K[2048,2560) V[2560,3072)), split bf16 outs, V^T.
// EPI 1: O-proj, f32 out = acc+bias+resid. EPI 2: MoE gate/up raw f32.
// EPI 3: MoE down raw f32 per slot.
template <int MT, int NS, bool SPLIT, int EPI>
__global__ __launch_bounds__(256) void gemm_ws(
    const unsigned short* __restrict__ Ah, const unsigned short* __restrict__ Al,
    int ldA,
    const float* __restrict__ W0, const float* __restrict__ W1,
    const float* __restrict__ W2,
    const float* __restrict__ b0, const float* __restrict__ b1,
    const float* __restrict__ b2,
    const float* __restrict__ resid,
    const int* __restrict__ counts, const int* __restrict__ arows,
    const int* __restrict__ orows,
    unsigned short* __restrict__ oh0, unsigned short* __restrict__ ol0,
    unsigned short* __restrict__ oh1, unsigned short* __restrict__ ol1,
    unsigned short* __restrict__ oh2, unsigned short* __restrict__ ol2,
    float* __restrict__ f0, float* __restrict__ f1,
    int M, int Kd) {
  constexpr int MG = MT * 64;
  constexpr int NR = NS * 16;
  constexpr int TPR = 256 / NR;   // threads per W row
  constexpr int CPT = 128 / TPR;  // fp32 cols per thread per chunk
  constexpr int NF4 = CPT / 4;    // float4 loads per thread per chunk
  constexpr int NPL = SPLIT ? 2 : 1;
  __shared__ __align__(16) unsigned short lw[2][NPL][NR][136];
  int tid = threadIdx.x;
  int l = tid & 63, w = tid >> 6;
  int g = l >> 4, q = l & 15;
  int n0 = blockIdx.x * NR;

  const float* Wb;
  const float* bias;
  int nloc = n0, e = 0, mat = 0;
  if constexpr (EPI == 0) {
    if (n0 < NHEAD * DHEAD) {
      Wb = W0; bias = b0;
    } else if (n0 < NHEAD * DHEAD + NKVH * DHEAD) {
      Wb = W1; bias = b1; nloc = n0 - NHEAD * DHEAD;
    } else {
      Wb = W2; bias = b2; nloc = n0 - (NHEAD * DHEAD + NKVH * DHEAD);
    }
  } else if constexpr (EPI == 1) {
    Wb = W0; bias = b0;
  } else if constexpr (EPI == 2) {
    e = blockIdx.z >> 1;
    mat = blockIdx.z & 1;
    Wb = (mat ? W1 : W0) + (size_t)e * INTER * HD;
    bias = (mat ? b1 : b0) + (size_t)e * INTER;
  } else {
    e = blockIdx.z;
    Wb = W0 + (size_t)e * HD * INTER;
    bias = b0 + (size_t)e * HD;
  }
  int cnt = (EPI >= 2) ? counts[e] : M;
  const float* wrow = Wb + (size_t)(nloc + tid / TPR) * Kd + (tid % TPR) * CPT;
  int wcc = (tid % TPR) * CPT;
  int wrr = tid / TPR;

  float4 wpre[NF4];
  auto stage = [&](int buf) {
#pragma unroll
    for (int j = 0; j < NF4; j += 2) {
      float v[8] = {wpre[j].x,     wpre[j].y,     wpre[j].z,     wpre[j].w,
                    wpre[j + 1].x, wpre[j + 1].y, wpre[j + 1].z, wpre[j + 1].w};
      short8 hh, ll;
#pragma unroll
      for (int jj = 0; jj < 8; ++jj) {
        if constexpr (SPLIT) {
          unsigned short h, lo;
          split2(v[jj], h, lo);
          hh[jj] = (short)h;
          ll[jj] = (short)lo;
        } else {
          hh[jj] = (short)f2bf(v[jj]);
        }
      }
      *(short8*)&lw[buf][0][wrr][wcc + j * 4] = hh;
      if constexpr (SPLIT) *(short8*)&lw[buf][NPL - 1][wrr][wcc + j * 4] = ll;
    }
  };

  for (int mg = blockIdx.y; mg * MG < cnt; mg += gridDim.y) {
    int mb = mg * MG + w * (MT * 16);
    const unsigned short* ap[MT];
    const unsigned short* apl[MT];
#pragma unroll
    for (int mt = 0; mt < MT; ++mt) {
      int mm = min(mb + mt * 16 + q, cnt - 1);
      int ar = (EPI >= 2) ? arows[e * SEQ + mm] : mm;
      ap[mt] = Ah + (size_t)ar * ldA + 8 * g;
      if constexpr (SPLIT) apl[mt] = Al + (size_t)ar * ldA + 8 * g;
    }
    f32x4 acc[MT][NS];
#pragma unroll
    for (int mt = 0; mt < MT; ++mt)
#pragma unroll
      for (int ns = 0; ns < NS; ++ns) acc[mt][ns] = (f32x4){0.f, 0.f, 0.f, 0.f};

    // prologue: W chunk-0 loads, A kh0/kh1 loads (fly under the W wait)
#pragma unroll
    for (int j = 0; j < NF4; ++j) wpre[j] = *(const float4*)(wrow + 4 * j);
    short8 ab[2][MT], abl[2][MT];
#pragma unroll
    for (int mt = 0; mt < MT; ++mt) {
      ab[0][mt] = *(const short8*)(ap[mt]);
      ab[1][mt] = *(const short8*)(ap[mt] + 32);
      if constexpr (SPLIT) {
        abl[0][mt] = *(const short8*)(apl[mt]);
        abl[1][mt] = *(const short8*)(apl[mt] + 32);
      }
    }
    stage(0);
    __syncthreads();

    int cb = 0;
    for (int kc = 0; kc < Kd; kc += 128, cb ^= 1) {
      bool more = (kc + 128 < Kd);
      if (more) {
#pragma unroll
        for (int j = 0; j < NF4; ++j)
          wpre[j] = *(const float4*)(wrow + kc + 128 + 4 * j);
      }
#pragma unroll
      for (int kh = 0; kh < 4; ++kh) {
        short8 acur[MT], acl[MT];
#pragma unroll
        for (int mt = 0; mt < MT; ++mt) {
          acur[mt] = ab[kh & 1][mt];
          if constexpr (SPLIT) acl[mt] = abl[kh & 1][mt];
        }
        int kn = kc + kh * 32 + 64;  // 2 kh-steps ahead
        if (kn < Kd) {
#pragma unroll
          for (int mt = 0; mt < MT; ++mt) {
            ab[kh & 1][mt] = *(const short8*)(ap[mt] + kn);
            if constexpr (SPLIT) abl[kh & 1][mt] = *(const short8*)(apl[mt] + kn);
          }
        }
        short8 wh[NS], wl[NS];
#pragma unroll
        for (int ns = 0; ns < NS; ++ns) {
          wh[ns] = *(const short8*)&lw[cb][0][ns * 16 + q][kh * 32 + 8 * g];
          if constexpr (SPLIT)
            wl[ns] = *(const short8*)&lw[cb][NPL - 1][ns * 16 + q][kh * 32 + 8 * g];
        }
#pragma unroll
        for (int mt = 0; mt < MT; ++mt)
#pragma unroll
          for (int ns = 0; ns < NS; ++ns) {
            acc[mt][ns] = mfma32(acur[mt], wh[ns], acc[mt][ns]);
            if constexpr (SPLIT) {
              acc[mt][ns] = mfma32(acur[mt], wl[ns], acc[mt][ns]);
              acc[mt][ns] = mfma32(acl[mt], wh[ns], acc[mt][ns]);
            }
          }
      }
      if (more) stage(cb ^ 1);
      __syncthreads();
    }
    // ---------------- epilogue ----------------
#pragma unroll
    for (int ns = 0; ns < NS; ++ns) {
      int ncol = nloc + ns * 16 + q;
      float bs = bias[ncol];
#pragma unroll
      for (int mt = 0; mt < MT; ++mt) {
#pragma unroll
        for (int r = 0; r < 4; ++r) {
          int mr = mb + mt * 16 + 4 * g + r;
          float val = acc[mt][ns][r] + bs;
          if constexpr (EPI == 0) {
            unsigned short h, lo;
            split2(val, h, lo);
            if (n0 < NHEAD * DHEAD) {
              oh0[(size_t)mr * (NHEAD * DHEAD) + ncol] = h;
              ol0[(size_t)mr * (NHEAD * DHEAD) + ncol] = lo;
            } else if (n0 < NHEAD * DHEAD + NKVH * DHEAD) {
              oh1[(size_t)mr * (NKVH * DHEAD) + ncol] = h;
              ol1[(size_t)mr * (NKVH * DHEAD) + ncol] = lo;
            } else {
              oh2[(size_t)ncol * SEQ + mr] = h;
              ol2[(size_t)ncol * SEQ + mr] = lo;
            }
          } else if constexpr (EPI == 1) {
            f0[(size_t)mr * HD + ncol] = val + resid[(size_t)mr * HD + ncol];
          } else if constexpr (EPI == 2) {
            if (mr < cnt) {
              int slot = orows[e * SEQ + mr];
              (mat ? f1 : f0)[(size_t)slot * INTER + ncol] = val;
            }
          } else {
            if (mr < cnt) {
              int slot = orows[e * SEQ + mr];
              f0[(size_t)slot * HD + ncol] = val;
            }
          }
        }
      }
    }
  }
}

// ---------------- Flash attention with sink, split precision ----------------
__global__ __launch_bounds__(256) void attn_kernel(
    const unsigned short* __restrict__ Qh, const unsigned short* __restrict__ Ql,
    const unsigned short* __restrict__ Kh, const unsigned short* __restrict__ Kl,
    const unsigned short* __restrict__ Vh, const unsigned short* __restrict__ Vl,
    const float* __restrict__ sinks, unsigned short* __restrict__ outh,
    unsigned short* __restrict__ outl) {
  __shared__ __align__(16) unsigned short pbuf[4][2][16][40];
  int l = threadIdx.x & 63, widx = threadIdx.x >> 6;
  int wid = blockIdx.x * 4 + widx;
  int head = wid >> 6, qt = wid & 63;
  int q0 = qt * 16;
  int g = l >> 4, q = l & 15;
  int kvh = head >> 2;
  size_t qoff = (size_t)(q0 + q) * (NHEAD * DHEAD) + head * DHEAD + 8 * g;
  short8 qh0 = *(const short8*)(Qh + qoff);
  short8 qh1 = *(const short8*)(Qh + qoff + 32);
  short8 ql0 = *(const short8*)(Ql + qoff);
  short8 ql1 = *(const short8*)(Ql + qoff + 32);
  float m = sinks[head];
  float lsum = 1.0f;
  f32x4 o[4] = {{0, 0, 0, 0}, {0, 0, 0, 0}, {0, 0, 0, 0}, {0, 0, 0, 0}};
  int qglob = q0 + q;
  for (int kt = 0; kt <= qt; kt += 2) {
    bool hasB = (kt + 1) <= qt;
    size_t koff = (size_t)(kt * 16 + q) * (NKVH * DHEAD) + kvh * DHEAD + 8 * g;
    f32x4 stA = {0, 0, 0, 0};
    {
      short8 kh0 = *(const short8*)(Kh + koff);
      short8 kh1 = *(const short8*)(Kh + koff + 32);
      short8 kl0 = *(const short8*)(Kl + koff);
      short8 kl1 = *(const short8*)(Kl + koff + 32);
      stA = mfma32(kh0, qh0, stA);
      stA = mfma32(kh0, ql0, stA);
      stA = mfma32(kl0, qh0, stA);
      stA = mfma32(kh1, qh1, stA);
      stA = mfma32(kh1, ql1, stA);
      stA = mfma32(kl1, qh1, stA);
    }
    f32x4 stB = {0, 0, 0, 0};
    if (hasB) {
      size_t koff2 = koff + (size_t)16 * (NKVH * DHEAD);
      short8 kh0 = *(const short8*)(Kh + koff2);
      short8 kh1 = *(const short8*)(Kh + koff2 + 32);
      short8 kl0 = *(const short8*)(Kl + koff2);
      short8 kl1 = *(const short8*)(Kl + koff2 + 32);
      stB = mfma32(kh0, qh0, stB);
      stB = mfma32(kh0, ql0, stB);
      stB = mfma32(kl0, qh0, stB);
      stB = mfma32(kh1, qh1, stB);
      stB = mfma32(kh1, ql1, stB);
      stB = mfma32(kl1, qh1, stB);
    }
    float sA[4], sB[4];
#pragma unroll
    for (int r = 0; r < 4; ++r) {
      int keyA = kt * 16 + 4 * g + r;
      sA[r] = (keyA <= qglob) ? stA[r] * SCALE : -1e30f;
      sB[r] = (hasB && keyA + 16 <= qglob) ? stB[r] * SCALE : -1e30f;
    }
    float mt = fmaxf(fmaxf(fmaxf(sA[0], sA[1]), fmaxf(sA[2], sA[3])),
                     fmaxf(fmaxf(sB[0], sB[1]), fmaxf(sB[2], sB[3])));
    mt = fmaxf(mt, __shfl_xor(mt, 16, 64));
    mt = fmaxf(mt, __shfl_xor(mt, 32, 64));
    float mnew = fmaxf(m, mt);
    float corr = __expf(m - mnew);
    float pA[4], pB[4];
    float rsum = 0.f;
#pragma unroll
    for (int r = 0; r < 4; ++r) {
      pA[r] = __expf(sA[r] - mnew);
      pB[r] = __expf(sB[r] - mnew);
      rsum += pA[r] + pB[r];
    }
    rsum += __shfl_xor(rsum, 16, 64);
    rsum += __shfl_xor(rsum, 32, 64);
    lsum = lsum * corr + rsum;
    m = mnew;
#pragma unroll
    for (int dt = 0; dt < 4; ++dt)
#pragma unroll
      for (int r = 0; r < 4; ++r) o[dt][r] *= corr;
    unsigned short ph[8], pl[8];
#pragma unroll
    for (int r = 0; r < 4; ++r) {
      split2(pA[r], ph[r], pl[r]);
      split2(pB[r], ph[4 + r], pl[4 + r]);
    }
    short4v wAh = {(short)ph[0], (short)ph[1], (short)ph[2], (short)ph[3]};
    short4v wBh = {(short)ph[4], (short)ph[5], (short)ph[6], (short)ph[7]};
    short4v wAl = {(short)pl[0], (short)pl[1], (short)pl[2], (short)pl[3]};
    short4v wBl = {(short)pl[4], (short)pl[5], (short)pl[6], (short)pl[7]};
    *(short4v*)&pbuf[widx][0][q][4 * g] = wAh;
    *(short4v*)&pbuf[widx][0][q][16 + 4 * g] = wBh;
    *(short4v*)&pbuf[widx][1][q][4 * g] = wAl;
    *(short4v*)&pbuf[widx][1][q][16 + 4 * g] = wBl;
    asm volatile("s_waitcnt lgkmcnt(0)" ::: "memory");
    short8 pbh = *(const short8*)&pbuf[widx][0][q][8 * g];
    short8 pbl = *(const short8*)&pbuf[widx][1][q][8 * g];
    size_t vbase = (size_t)(kvh * DHEAD) * SEQ + kt * 16 + 8 * g;
#pragma unroll
    for (int dt = 0; dt < 4; ++dt) {
      size_t voff = vbase + (size_t)(dt * 16 + q) * SEQ;
      short8 vh8 = *(const short8*)(Vh + voff);
      short8 vl8 = *(const short8*)(Vl + voff);
      o[dt] = mfma32(vh8, pbh, o[dt]);
      o[dt] = mfma32(vh8, pbl, o[dt]);
      o[dt] = mfma32(vl8, pbh, o[dt]);
    }
  }
  float inv = 1.0f / lsum;
#pragma unroll
  for (int dt = 0; dt < 4; ++dt)
#pragma unroll
    for (int r = 0; r < 4; ++r) {
      float val = o[dt][r] * inv;
      unsigned short h, lo;
      split2(val, h, lo);
      size_t idx = (size_t)qglob * (NHEAD * DHEAD) + head * DHEAD + dt * 16 + 4 * g + r;
      outh[idx] = h;
      outl[idx] = lo;
    }
}

// ---------------- Router: fp64 norm + logits, top-2, slot/weight lists -------
__global__ __launch_bounds__(64) void router_kernel(
    const float* __restrict__ h, const float* __restrict__ gamma,
    const float* __restrict__ rw, const float* __restrict__ rb,
    float* __restrict__ wsel, int* __restrict__ counts,
    int* __restrict__ lists, int* __restrict__ slotof) {
  int t = blockIdx.x;
  int l = threadIdx.x;
  const float* hr = h + (size_t)t * HD;
  double ss = 0.0;
  for (int i = l; i < HD; i += 64) {
    double x = (double)hr[i];
    ss += x * x;
  }
#pragma unroll
  for (int off = 32; off; off >>= 1) ss += __shfl_xor(ss, off, 64);
  double rs = rsqrt(ss * (1.0 / HD) + 1e-5);
  double acc[NEXP];
#pragma unroll
  for (int e = 0; e < NEXP; ++e) acc[e] = 0.0;
  for (int i = l; i < HD; i += 64) {
    double xh = (double)hr[i] * rs * (double)gamma[i];
#pragma unroll
    for (int e = 0; e < NEXP; ++e) acc[e] += xh * (double)rw[e * HD + i];
  }
#pragma unroll
  for (int e = 0; e < NEXP; ++e)
#pragma unroll
    for (int off = 32; off; off >>= 1) acc[e] += __shfl_xor(acc[e], off, 64);
  if (l == 0) {
    double lg[NEXP];
#pragma unroll
    for (int e = 0; e < NEXP; ++e) lg[e] = acc[e] + (double)rb[e];
    int e0 = 0;
#pragma unroll
    for (int e = 1; e < NEXP; ++e)
      if (lg[e] > lg[e0]) e0 = e;
    int e1 = -1;
#pragma unroll
    for (int e = 0; e < NEXP; ++e)
      if (e != e0 && (e1 < 0 || lg[e] > lg[e1])) e1 = e;
    double d = exp(lg[e1] - lg[e0]);
    float p0 = (float)(1.0 / (1.0 + d)), p1 = (float)(d / (1.0 + d));
    wsel[2 * t] = p0;
    wsel[2 * t + 1] = p1;
    int s0 = atomicAdd(&counts[e0], 1);
    lists[e0 * SEQ + s0] = t;
    slotof[e0 * SEQ + s0] = 2 * t;
    int s1 = atomicAdd(&counts[e1], 1);
    lists[e1 * SEQ + s1] = t;
    slotof[e1 * SEQ + s1] = 2 * t + 1;
  }
}

// ---------------- MoE activation: raw gate/up -> gated bf16 -----------------
__global__ __launch_bounds__(256) void act_kernel(
    const float* __restrict__ rg, const float* __restrict__ ru,
    unsigned short* __restrict__ gated) {
  size_t base = (size_t)blockIdx.x * INTER + threadIdx.x * 8;
  float4 g0 = *(const float4*)(rg + base);
  float4 g1 = *(const float4*)(rg + base + 4);
  float4 u0 = *(const float4*)(ru + base);
  float4 u1 = *(const float4*)(ru + base + 4);
  float gv[8] = {g0.x, g0.y, g0.z, g0.w, g1.x, g1.y, g1.z, g1.w};
  float uv[8] = {u0.x, u0.y, u0.z, u0.w, u1.x, u1.y, u1.z, u1.w};
  short8 o;
#pragma unroll
  for (int j = 0; j < 8; ++j) {
    float gc = fminf(gv[j], LIMIT);
    float uc = fminf(fmaxf(uv[j], -LIMIT), LIMIT);
    float glu = gc / (1.f + __expf(-ALPHA * gc));
    o[j] = (short)f2bf((uc + 1.f) * glu);
  }
  *(short8*)(gated + base) = o;
}

// ---------------- Final: out = h + w0*down[2t] + w1*down[2t+1] --------------
__global__ __launch_bounds__(256) void reduce_kernel(
    const float* __restrict__ hbuf, const float* __restrict__ scr,
    const float* __restrict__ wsel, float* __restrict__ out) {
  int t = blockIdx.x;
  int c = threadIdx.x * 8;
  float w0 = wsel[2 * t], w1 = wsel[2 * t + 1];
  size_t hb = (size_t)t * HD + c;
  size_t s0 = (size_t)(2 * t) * HD + c;
  size_t s1 = (size_t)(2 * t + 1) * HD + c;
#pragma unroll
  for (int j = 0; j < 2; ++j) {
    float4 hv = *(const float4*)(hbuf + hb + 4 * j);
    float4 a = *(const float4*)(scr + s0 + 4 * j);
    float4 b = *(const float4*)(scr + s1 + 4 * j);
    float4 r;
    r.x = hv.x + w0 * a.x + w1 * b.x;
    r.y = hv.y + w0 * a.y + w1 * b.y;
    r.z = hv.z + w0 * a.z + w1 * b.z;
    r.w = hv.w + w0 * a.w + w1 * b.w;
    *(float4*)(out + hb + 4 * j) = r;
  }
}

extern "C" void kernel_launch(void* const* d_in, const int* in_sizes, int n_in,
                              void* d_out, int out_size, void* d_ws,
                              size_t ws_size, hipStream_t stream) {
  const float* x = (const float*)d_in[0];
  const float* ln1 = (const float*)d_in[2];
  const float* ln2 = (const float*)d_in[3];
  const float* Wq = (const float*)d_in[4];
  const float* bq = (const float*)d_in[5];
  const float* Wk = (const float*)d_in[6];
  const float* bk = (const float*)d_in[7];
  const float* Wv = (const float*)d_in[8];
  const float* bv = (const float*)d_in[9];
  const float* Wo = (const float*)d_in[10];
  const float* bo = (const float*)d_in[11];
  const float* sinks = (const float*)d_in[12];
  const float* rw = (const float*)d_in[13];
  const float* rb = (const float*)d_in[14];
  const float* Wg = (const float*)d_in[15];
  const float* bg = (const float*)d_in[16];
  const float* Wu = (const float*)d_in[17];
  const float* bu = (const float*)d_in[18];
  const float* Wd = (const float*)d_in[19];
  const float* bd = (const float*)d_in[20];
  float* out = (float*)d_out;

  char* ws = (char*)d_ws;
  size_t off = 0;
  auto alloc = [&](size_t bytes) {
    void* p = ws + off;
    off += (bytes + 255) & ~(size_t)255;
    return p;
  };
  unsigned short* xnh = (unsigned short*)alloc((size_t)SEQ * HD * 2);
  unsigned short* xnl = (unsigned short*)alloc((size_t)SEQ * HD * 2);
  unsigned short* qbh = (unsigned short*)alloc((size_t)SEQ * NHEAD * DHEAD * 2);
  unsigned short* qbl = (unsigned short*)alloc((size_t)SEQ * NHEAD * DHEAD * 2);
  unsigned short* kbh = (unsigned short*)alloc((size_t)SEQ * NKVH * DHEAD * 2);
  unsigned short* kbl = (unsigned short*)alloc((size_t)SEQ * NKVH * DHEAD * 2);
  unsigned short* vth = (unsigned short*)alloc((size_t)NKVH * DHEAD * SEQ * 2);
  unsigned short* vtl = (unsigned short*)alloc((size_t)NKVH * DHEAD * SEQ * 2);
  unsigned short* ath = (unsigned short*)alloc((size_t)SEQ * NHEAD * DHEAD * 2);
  unsigned short* atl = (unsigned short*)alloc((size_t)SEQ * NHEAD * DHEAD * 2);
  float* hbuf = (float*)alloc((size_t)SEQ * HD * 4);
  unsigned short* hn = (unsigned short*)alloc((size_t)SEQ * HD * 2);
  float* wsel = (float*)alloc((size_t)SEQ * 2 * 4);
  int* counts = (int*)alloc(NEXP * 4);
  int* lists = (int*)alloc((size_t)NEXP * SEQ * 4);
  int* slotof = (int*)alloc((size_t)NEXP * SEQ * 4);
  float* rawg = (float*)alloc((size_t)2 * SEQ * INTER * 4);
  float* rawu = (float*)alloc((size_t)2 * SEQ * INTER * 4);
  unsigned short* gated = (unsigned short*)alloc((size_t)2 * SEQ * INTER * 2);
  float* scr = rawg;  // down-proj scratch aliases rawg (stream-ordered safe)
  (void)ws_size;
  (void)off;

  rmsnorm_split_kernel<<<SEQ, 256, 0, stream>>>(x, ln1, xnh, xnl);
  // fused QKV projection: N = 2048 + 512 + 512 = 3072 cols
  gemm_ws<4, 2, true, 0><<<dim3(96, 4, 1), 256, 0, stream>>>(
      xnh, xnl, HD, Wq, Wk, Wv, bq, bk, bv, nullptr, nullptr, nullptr, nullptr,
      qbh, qbl, kbh, kbl, vth, vtl, nullptr, nullptr, SEQ, HD);
  attn_kernel<<<NHEAD * 64 / 4, 256, 0, stream>>>(qbh, qbl, kbh, kbl, vth, vtl,
                                                  sinks, ath, atl);
  gemm_ws<4, 2, true, 1><<<dim3(64, 4, 1), 256, 0, stream>>>(
      ath, atl, NHEAD * DHEAD, Wo, nullptr, nullptr, bo, nullptr, nullptr, x,
      nullptr, nullptr, nullptr, nullptr, nullptr, nullptr, nullptr, nullptr,
      nullptr, hbuf, nullptr, SEQ, NHEAD * DHEAD);
  rmsnorm_plain_kernel<<<SEQ, 256, 0, stream>>>(hbuf, ln2, hn);
  hipMemsetAsync(counts, 0, NEXP * sizeof(int), stream);
  router_kernel<<<SEQ, 64, 0, stream>>>(hbuf, ln2, rw, rb, wsel, counts, lists,
                                        slotof);
  // gate+up fused over z (e*2 + mat): 64 n-blocks x 16 z = 1024 blocks
  gemm_ws<5, 2, false, 2><<<dim3(64, 1, 16), 256, 0, stream>>>(
      hn, nullptr, HD, Wg, Wu, nullptr, bg, bu, nullptr, nullptr, counts, lists,
      slotof, nullptr, nullptr, nullptr, nullptr, nullptr, nullptr, rawg, rawu,
      SEQ, HD);
  act_kernel<<<2 * SEQ, 256, 0, stream>>>(rawg, rawu, gated);
  gemm_ws<5, 2, false, 3><<<dim3(64, 1, 8), 256, 0, stream>>>(
      gated, nullptr, INTER, Wd, nullptr, nullptr, bd, nullptr, nullptr,
      nullptr, counts, slotof, slotof, nullptr, nullptr, nullptr, nullptr,
      nullptr, nullptr, scr, nullptr, SEQ, INTER);
  reduce_kernel<<<SEQ, 256, 0, stream>>>(hbuf, scr, wsel, out);
}